// Round 10
// baseline (853.717 us; speedup 1.0000x reference)
//
#include <hip/hip_runtime.h>
#include <hip/hip_bf16.h>
#include <math.h>

// B=4 S=1024 DM=256 H=8 HD=32 CIN=23 E=16 D2=512 HE=1365 2HE=2730 CAP=128
#define CAPN 128

typedef short short8 __attribute__((ext_vector_type(8)));
typedef short short4v __attribute__((ext_vector_type(4)));
typedef float f32x4 __attribute__((ext_vector_type(4)));

__device__ __forceinline__ float gelu_f(float x){
  return 0.5f*x*(1.0f+erff(x*0.7071067811865476f));
}
__device__ __forceinline__ void split2(float v, __hip_bfloat16& h, __hip_bfloat16& l){
  h = __float2bfloat16(v);
  l = __float2bfloat16(v - __bfloat162float(h));
}
__device__ __forceinline__ void split2s(float v, short& h, short& l){
  __hip_bfloat16 hh = __float2bfloat16(v);
  __hip_bfloat16 ll = __float2bfloat16(v - __bfloat162float(hh));
  h = *(short*)&hh; l = *(short*)&ll;
}

// ---------------- topo
__global__ __launch_bounds__(256) void topo_kernel(
    const float* __restrict__ K, const float* __restrict__ Q,
    const float* __restrict__ w, const float* __restrict__ b,
    __hip_bfloat16* __restrict__ khi, __hip_bfloat16* __restrict__ klo,
    __hip_bfloat16* __restrict__ qhi, __hip_bfloat16* __restrict__ qlo,
    float* __restrict__ qf32)
{
  int idx = blockIdx.x*256 + threadIdx.x;   // 2M
  int d = idx & 255;
  int r = idx >> 8;
  int bb = r >> 11;
  int n  = r & 2047;
  const float* src = (n < 1024) ? (K + ((bb<<10) + n)*3)
                                : (Q + ((bb<<10) + (n-1024))*3);
  float v = b[d] + src[0]*w[d] + src[1]*w[256+d] + src[2]*w[512+d];
  v = gelu_f(v);
  int off = (((bb<<10) + (n & 1023))<<8) + d;
  __hip_bfloat16 h, l; split2(v, h, l);
  if (n < 1024){ khi[off] = h; klo[off] = l; }
  else         { qhi[off] = h; qlo[off] = l; qf32[off] = v; }
}

// ---------------- values
__global__ __launch_bounds__(256) void values_kernel(
    const float* __restrict__ V, const float* __restrict__ w,
    const float* __restrict__ b,
    __hip_bfloat16* __restrict__ vhi, __hip_bfloat16* __restrict__ vlo)
{
  int idx = blockIdx.x*256 + threadIdx.x;
  int d = idx & 255; int r = idx >> 8;
  const float* src = V + r*23;
  float acc = b[d];
  #pragma unroll
  for (int c=0;c<23;c++) acc += src[c]*w[c*256+d];
  acc = gelu_f(acc);
  __hip_bfloat16 h, l; split2(acc, h, l);
  vhi[idx] = h; vlo[idx] = l;
}

// ---------------- split-bf16 "fp32" MFMA GEMM (pipelined, optional split-K)
#define SLP 40
__global__ __launch_bounds__(256) void sgemm_kernel(
    const __hip_bfloat16* __restrict__ Ah_, const __hip_bfloat16* __restrict__ Al_,
    int lda, long sA,
    const __hip_bfloat16* __restrict__ Wh_, const __hip_bfloat16* __restrict__ Wl_,
    int ldw, long sW,
    const float* __restrict__ bias, int nbias, int bsplit, int bsplitPad, long sB,
    const float* __restrict__ R, int ldr,
    float* __restrict__ C, int ldc, long sC,
    int K, int act,
    float* __restrict__ P, long pz, int splitK)
{
  int z = blockIdx.z / splitK;
  int kc = blockIdx.z - z*splitK;
  const short* Ah = (const short*)Ah_ + (long)z*sA;
  const short* Al = (const short*)Al_ + (long)z*sA;
  const short* Wh = (const short*)Wh_ + (long)z*sW;
  const short* Wl = (const short*)Wl_ + (long)z*sW;
  int bm = blockIdx.y*128, bn = blockIdx.x*128;
  int tid = threadIdx.x, lane = tid & 63, wave = tid >> 6;
  int wm = (wave & 1)*64, wn = (wave >> 1)*64;

  __shared__ short AsH[128*SLP], AsL[128*SLP], BsH[128*SLP], BsL[128*SLP];

  f32x4 acc[4][4];
  f32x4 zero4 = {0.f,0.f,0.f,0.f};
  #pragma unroll
  for (int i=0;i<4;i++)
    #pragma unroll
    for (int j=0;j<4;j++) acc[i][j] = zero4;

  int srow = tid >> 1, scol = (tid & 1)*16;
  int ml = lane & 15, q = lane >> 4;
  long abase = (long)(bm+srow)*lda + scol;
  long bbase = (long)(bn+srow)*ldw + scol;

  int Kc = K / splitK;
  int kbeg = kc * Kc, kend = kbeg + Kc;

  short8 ah0 = *(const short8*)&Ah[abase + kbeg];
  short8 ah1 = *(const short8*)&Ah[abase + kbeg + 8];
  short8 al0 = *(const short8*)&Al[abase + kbeg];
  short8 al1 = *(const short8*)&Al[abase + kbeg + 8];
  short8 bh0 = *(const short8*)&Wh[bbase + kbeg];
  short8 bh1 = *(const short8*)&Wh[bbase + kbeg + 8];
  short8 bl0 = *(const short8*)&Wl[bbase + kbeg];
  short8 bl1 = *(const short8*)&Wl[bbase + kbeg + 8];

  for (int k0 = kbeg; k0 < kend; k0 += 32){
    __syncthreads();
    *(short8*)&AsH[srow*SLP + scol]     = ah0;
    *(short8*)&AsH[srow*SLP + scol + 8] = ah1;
    *(short8*)&AsL[srow*SLP + scol]     = al0;
    *(short8*)&AsL[srow*SLP + scol + 8] = al1;
    *(short8*)&BsH[srow*SLP + scol]     = bh0;
    *(short8*)&BsH[srow*SLP + scol + 8] = bh1;
    *(short8*)&BsL[srow*SLP + scol]     = bl0;
    *(short8*)&BsL[srow*SLP + scol + 8] = bl1;
    __syncthreads();
    if (k0 + 32 < kend){
      long ab = abase + k0 + 32;
      long bb2 = bbase + k0 + 32;
      ah0 = *(const short8*)&Ah[ab];
      ah1 = *(const short8*)&Ah[ab + 8];
      al0 = *(const short8*)&Al[ab];
      al1 = *(const short8*)&Al[ab + 8];
      bh0 = *(const short8*)&Wh[bb2];
      bh1 = *(const short8*)&Wh[bb2 + 8];
      bl0 = *(const short8*)&Wl[bb2];
      bl1 = *(const short8*)&Wl[bb2 + 8];
    }
    short8 afh[4], afl[4], bfh[4], bfl[4];
    #pragma unroll
    for (int i=0;i<4;i++){
      afh[i] = *(const short8*)&AsH[(wm + 16*i + ml)*SLP + q*8];
      afl[i] = *(const short8*)&AsL[(wm + 16*i + ml)*SLP + q*8];
    }
    #pragma unroll
    for (int j=0;j<4;j++){
      bfh[j] = *(const short8*)&BsH[(wn + 16*j + ml)*SLP + q*8];
      bfl[j] = *(const short8*)&BsL[(wn + 16*j + ml)*SLP + q*8];
    }
    #pragma unroll
    for (int i=0;i<4;i++)
      #pragma unroll
      for (int j=0;j<4;j++){
        acc[i][j] = __builtin_amdgcn_mfma_f32_16x16x32_bf16(afh[i], bfh[j], acc[i][j], 0,0,0);
        acc[i][j] = __builtin_amdgcn_mfma_f32_16x16x32_bf16(afh[i], bfl[j], acc[i][j], 0,0,0);
        acc[i][j] = __builtin_amdgcn_mfma_f32_16x16x32_bf16(afl[i], bfh[j], acc[i][j], 0,0,0);
      }
  }

  if (P){   // raw partial store (split-K path)
    float* Pb = P + (long)blockIdx.z * pz;
    #pragma unroll
    for (int i=0;i<4;i++)
      #pragma unroll
      for (int r=0;r<4;r++){
        int gm = bm + wm + 16*i + q*4 + r;
        #pragma unroll
        for (int j=0;j<4;j++){
          int gn = bn + wn + 16*j + ml;
          Pb[(long)gm*ldc + gn] = acc[i][j][r];
        }
      }
    return;
  }

  const float* biasz = bias ? bias + (long)z*sB : nullptr;
  long coff = (long)z*sC;
  #pragma unroll
  for (int i=0;i<4;i++){
    #pragma unroll
    for (int r=0;r<4;r++){
      int gm = bm + wm + 16*i + q*4 + r;
      #pragma unroll
      for (int j=0;j<4;j++){
        int gn = bn + wn + 16*j + ml;
        float v = acc[i][j][r];
        if (biasz){
          int bi;
          if (bsplit){
            if (gn < bsplit) bi = gn;
            else if (gn >= bsplitPad && gn < bsplitPad + (nbias - bsplit)) bi = gn - (bsplitPad - bsplit);
            else bi = -1;
          } else bi = (gn < nbias) ? gn : -1;
          if (bi >= 0) v += biasz[bi];
        }
        if (act == 1) v = gelu_f(v);
        if (R) v += R[(long)gm*ldr + gn];
        C[coff + (long)gm*ldc + gn] = v;
      }
    }
  }
}

// ---------------- pure-bf16 MFMA GEMM (pipelined, optional split-K)
#define LP 56
__global__ __launch_bounds__(256) void bgemm_kernel(
    const __hip_bfloat16* __restrict__ A, int lda, long sA,
    const __hip_bfloat16* __restrict__ WT, int ldw, long sW,
    const float* __restrict__ bias, int nbias, int bsplit, int bsplitPad, long sB,
    const float* __restrict__ R, int ldr, long sR,
    void* __restrict__ C, int ldc, long sC, int cIsBf16,
    int K, int act,
    float* __restrict__ P, long pz, int splitK)
{
  int z = blockIdx.z / splitK;
  int kc = blockIdx.z - z*splitK;
  const short* Ab = (const short*)A + (long)z*sA;
  const short* Bb = (const short*)WT + (long)z*sW;
  int bm = blockIdx.y*128, bn = blockIdx.x*128;
  int tid = threadIdx.x, lane = tid & 63, wave = tid >> 6;
  int wm = (wave & 1)*64, wn = (wave >> 1)*64;

  __shared__ short As[128*LP];
  __shared__ short Bs[128*LP];

  f32x4 acc[4][4];
  f32x4 zero4 = {0.f,0.f,0.f,0.f};
  #pragma unroll
  for (int i=0;i<4;i++)
    #pragma unroll
    for (int j=0;j<4;j++) acc[i][j] = zero4;

  int g0 = tid, g1 = tid + 256;
  int r0 = g0 >> 2, c0 = (g0 & 3) * 8;
  int r1 = g1 >> 2, c1 = (g1 & 3) * 8;
  int ml = lane & 15, q = lane >> 4;
  long a0base = (long)(bm+r0)*lda + c0;
  long a1base = (long)(bm+r1)*lda + c1;
  long b0base = (long)(bn+r0)*ldw + c0;
  long b1base = (long)(bn+r1)*ldw + c1;

  int Kc = K / splitK;
  int kbeg = kc * Kc, kend = kbeg + Kc;

  short8 av0 = *(const short8*)&Ab[a0base + kbeg];
  short8 av1 = *(const short8*)&Ab[a1base + kbeg];
  short8 bv0 = *(const short8*)&Bb[b0base + kbeg];
  short8 bv1 = *(const short8*)&Bb[b1base + kbeg];

  for (int k0 = kbeg; k0 < kend; k0 += 32){
    __syncthreads();
    *(short8*)&As[r0*LP + c0] = av0;
    *(short8*)&As[r1*LP + c1] = av1;
    *(short8*)&Bs[r0*LP + c0] = bv0;
    *(short8*)&Bs[r1*LP + c1] = bv1;
    __syncthreads();
    if (k0 + 32 < kend){
      av0 = *(const short8*)&Ab[a0base + k0 + 32];
      av1 = *(const short8*)&Ab[a1base + k0 + 32];
      bv0 = *(const short8*)&Bb[b0base + k0 + 32];
      bv1 = *(const short8*)&Bb[b1base + k0 + 32];
    }
    short8 af[4], bfv[4];
    #pragma unroll
    for (int i=0;i<4;i++) af[i]  = *(const short8*)&As[(wm + 16*i + ml)*LP + q*8];
    #pragma unroll
    for (int j=0;j<4;j++) bfv[j] = *(const short8*)&Bs[(wn + 16*j + ml)*LP + q*8];
    #pragma unroll
    for (int i=0;i<4;i++)
      #pragma unroll
      for (int j=0;j<4;j++)
        acc[i][j] = __builtin_amdgcn_mfma_f32_16x16x32_bf16(af[i], bfv[j], acc[i][j], 0,0,0);
  }

  if (P){
    float* Pb = P + (long)blockIdx.z * pz;
    #pragma unroll
    for (int i=0;i<4;i++)
      #pragma unroll
      for (int r=0;r<4;r++){
        int gm = bm + wm + 16*i + q*4 + r;
        #pragma unroll
        for (int j=0;j<4;j++){
          int gn = bn + wn + 16*j + ml;
          Pb[(long)gm*ldc + gn] = acc[i][j][r];
        }
      }
    return;
  }

  const float* biasz = bias ? bias + (long)z*sB : nullptr;
  const float* Rz = R ? R + (long)z*sR : nullptr;
  long coff = (long)z*sC;
  #pragma unroll
  for (int i=0;i<4;i++){
    #pragma unroll
    for (int r=0;r<4;r++){
      int gm = bm + wm + 16*i + q*4 + r;
      #pragma unroll
      for (int j=0;j<4;j++){
        int gn = bn + wn + 16*j + ml;
        float v = acc[i][j][r];
        if (biasz){
          int bi;
          if (bsplit){
            if (gn < bsplit) bi = gn;
            else if (gn >= bsplitPad && gn < bsplitPad + (nbias - bsplit)) bi = gn - (bsplitPad - bsplit);
            else bi = -1;
          } else bi = (gn < nbias) ? gn : -1;
          if (bi >= 0) v += biasz[bi];
        }
        if (act == 2) v = (v > 0.f) ? v : 0.01f*v;
        if (Rz) v += Rz[(long)gm*ldr + gn];
        if (cIsBf16) ((__hip_bfloat16*)C)[coff + (long)gm*ldc + gn] = __float2bfloat16(v);
        else         ((float*)C)[coff + (long)gm*ldc + gn] = v;
      }
    }
  }
}

// ---------------- split-K reduce
__global__ __launch_bounds__(256) void reduce_kernel(
    const float* __restrict__ P, long zStride, int nsplit,
    const float* __restrict__ bias,
    const float* __restrict__ R, float* __restrict__ out,
    int Nmask, int logN, int ldOut, int act, long total)
{
  long idx = (long)blockIdx.x*256 + threadIdx.x;
  if (idx >= total) return;
  long zz = idx / zStride;
  long rem = idx - zz*zStride;
  const float* Pb = P + zz*(long)nsplit*zStride + rem;
  float v = 0.f;
  for (int k=0;k<nsplit;k++) v += Pb[(long)k*zStride];
  int n = (int)(idx & Nmask);
  long row = idx >> logN;
  if (bias) v += bias[n];
  if (act == 1) v = gelu_f(v);
  long o = row*(long)ldOut + n;
  if (R) v += R[o];
  out[o] = v;
}

// ---------------- weight transpose+convert (single bf16 out, z-batched)
__global__ __launch_bounds__(256) void convT_kernel(
    const float* __restrict__ W, int N, int K, long sW,
    __hip_bfloat16* __restrict__ out, int Npad, int Kpad, long sO,
    int split, int splitPad)
{
  int z = blockIdx.z;
  int n0 = blockIdx.x*64, k0 = blockIdx.y*64;
  int tid = threadIdx.x;
  __shared__ float lds[64][65];
  #pragma unroll
  for (int i=0;i<16;i++){
    int e = tid + i*256;
    int kl = e >> 6, c = e & 63;
    int np = n0 + c;
    int ns;
    if (split){
      if (np < split) ns = np;
      else if (np >= splitPad && np < splitPad + (N - split)) ns = np - (splitPad - split);
      else ns = -1;
    } else ns = (np < N) ? np : -1;
    int k = k0 + kl;
    float v = (ns >= 0 && k < K) ? W[(long)z*sW + (long)k*N + ns] : 0.f;
    lds[kl][c] = v;
  }
  __syncthreads();
  #pragma unroll
  for (int i=0;i<16;i++){
    int e = tid + i*256;
    int nl = e >> 6, kl = e & 63;
    out[(long)z*sO + (long)(n0+nl)*Kpad + k0 + kl] = __float2bfloat16(lds[kl][nl]);
  }
}

// ---------------- weight transpose+convert with hi/lo split
__global__ __launch_bounds__(256) void convT2_kernel(
    const float* __restrict__ W, int N, int K,
    __hip_bfloat16* __restrict__ outh, __hip_bfloat16* __restrict__ outl,
    int Npad, int Kpad, int split, int splitPad)
{
  int n0 = blockIdx.x*64, k0 = blockIdx.y*64;
  int tid = threadIdx.x;
  __shared__ float lds[64][65];
  #pragma unroll
  for (int i=0;i<16;i++){
    int e = tid + i*256;
    int kl = e >> 6, c = e & 63;
    int np = n0 + c;
    int ns;
    if (split){
      if (np < split) ns = np;
      else if (np >= splitPad && np < splitPad + (N - split)) ns = np - (splitPad - split);
      else ns = -1;
    } else ns = (np < N) ? np : -1;
    int k = k0 + kl;
    float v = (ns >= 0 && k < K) ? W[(long)k*N + ns] : 0.f;
    lds[kl][c] = v;
  }
  __syncthreads();
  #pragma unroll
  for (int i=0;i<16;i++){
    int e = tid + i*256;
    int nl = e >> 6, kl = e & 63;
    float v = lds[kl][nl];
    __hip_bfloat16 h, l; split2(v, h, l);
    long o = (long)(n0+nl)*Kpad + k0 + kl;
    outh[o] = h; outl[o] = l;
  }
}

// ---------------- bias pack for z-batched QKV
__global__ void pack_bias_kernel(const float* bq, const float* bk, const float* bv, float* out){
  int i = blockIdx.x*256 + threadIdx.x;
  if (i < 256) out[i] = bq[i];
  else if (i < 512) out[i] = bk[i-256];
  else if (i < 768) out[i] = bv[i-512];
}

// ---------------- attention prep: Q (scaled) and K fp32 -> hi/lo bf16
__global__ __launch_bounds__(256) void qksplit_kernel(
    const float* __restrict__ QP,
    __hip_bfloat16* __restrict__ qsh, __hip_bfloat16* __restrict__ qsl,
    __hip_bfloat16* __restrict__ ksh, __hip_bfloat16* __restrict__ ksl)
{
  int idx = blockIdx.x*256 + threadIdx.x;   // 1048576
  float qv = QP[idx] * 0.17677669529663687f;
  __hip_bfloat16 h, l;
  split2(qv, h, l); qsh[idx] = h; qsl[idx] = l;
  float kv = QP[1048576 + idx];
  split2(kv, h, l); ksh[idx] = h; ksl[idx] = l;
}

// ---------------- attention prep: V fp32 [s][256] -> V^T hi/lo [bh][32 d][1024 s]
__global__ __launch_bounds__(256) void vtrans_kernel(
    const float* __restrict__ VP,
    __hip_bfloat16* __restrict__ vth, __hip_bfloat16* __restrict__ vtl)
{
  int bh = blockIdx.y, bb = bh >> 3, h = bh & 7;
  int s0 = blockIdx.x*64;
  int tid = threadIdx.x;
  __shared__ float t[64][33];
  #pragma unroll
  for (int p=0;p<8;p++){
    int sl = (tid>>5) + p*8;
    int d = tid & 31;
    t[sl][d] = VP[((bb<<10)+s0+sl)*256 + h*32 + d];
  }
  __syncthreads();
  #pragma unroll
  for (int p=0;p<8;p++){
    int dl = (tid>>6) + p*4;
    int s = tid & 63;
    float v = t[s][dl];
    __hip_bfloat16 hh, ll; split2(v, hh, ll);
    vth[(bh*32+dl)*1024 + s0 + s] = hh;
    vtl[(bh*32+dl)*1024 + s0 + s] = ll;
  }
}

// ---------------- MFMA flash attention v2 (transposed-S softmax + MFMA row-sum)
#define KSP 40
__global__ __launch_bounds__(256) void attn_mfma_kernel(
    const __hip_bfloat16* __restrict__ qsh_, const __hip_bfloat16* __restrict__ qsl_,
    const __hip_bfloat16* __restrict__ ksh_, const __hip_bfloat16* __restrict__ ksl_,
    const __hip_bfloat16* __restrict__ vth_, const __hip_bfloat16* __restrict__ vtl_,
    __hip_bfloat16* __restrict__ aoh, __hip_bfloat16* __restrict__ aol)
{
  const short* qsh = (const short*)qsh_; const short* qsl = (const short*)qsl_;
  const short* ksh = (const short*)ksh_; const short* ksl = (const short*)ksl_;
  const short* vth = (const short*)vth_; const short* vtl = (const short*)vtl_;
  int bh = blockIdx.y, bb = bh >> 3, h = bh & 7;
  int tid = threadIdx.x, lane = tid & 63, wave = tid >> 6;
  int ml = lane & 15, quad = lane >> 4;
  int q0 = blockIdx.x*64 + wave*16;

  __shared__ short KhS[32*KSP], KlS[32*KSP], VhS[32*KSP], VlS[32*KSP];
  __shared__ short PhS[4][16*KSP], PlS[4][16*KSP];
  short* Phw = PhS[wave]; short* Plw = PlS[wave];

  int qrow = (bb<<10) + q0 + ml;
  short8 qfh = *(const short8*)&qsh[qrow*256 + h*32 + quad*8];
  short8 qfl = *(const short8*)&qsl[qrow*256 + h*32 + quad*8];

  short8 ones;
  #pragma unroll
  for (int i=0;i<8;i++) ones[i] = (short)0x3F80;   // bf16 1.0

  f32x4 O0 = {0.f,0.f,0.f,0.f}, O1 = {0.f,0.f,0.f,0.f};
  f32x4 Lacc = {0.f,0.f,0.f,0.f};
  float m_s = -INFINITY;

  int sr = tid >> 3, sc = (tid & 7)*4;
  for (int k0 = 0; k0 < 1024; k0 += 32){
    int krow = (bb<<10) + k0 + sr;
    short4v kvh = *(const short4v*)&ksh[krow*256 + h*32 + sc];
    short4v kvl = *(const short4v*)&ksl[krow*256 + h*32 + sc];
    short4v vvh = *(const short4v*)&vth[(bh*32+sr)*1024 + k0 + sc];
    short4v vvl = *(const short4v*)&vtl[(bh*32+sr)*1024 + k0 + sc];
    __syncthreads();
    *(short4v*)&KhS[sr*KSP + sc] = kvh;
    *(short4v*)&KlS[sr*KSP + sc] = kvl;
    *(short4v*)&VhS[sr*KSP + sc] = vvh;
    *(short4v*)&VlS[sr*KSP + sc] = vvl;
    __syncthreads();
    short8 kb0h = *(const short8*)&KhS[ml*KSP + quad*8];
    short8 kb0l = *(const short8*)&KlS[ml*KSP + quad*8];
    short8 kb1h = *(const short8*)&KhS[(16+ml)*KSP + quad*8];
    short8 kb1l = *(const short8*)&KlS[(16+ml)*KSP + quad*8];
    f32x4 S0 = {0.f,0.f,0.f,0.f}, S1 = {0.f,0.f,0.f,0.f};
    S0 = __builtin_amdgcn_mfma_f32_16x16x32_bf16(kb0l, qfh, S0, 0,0,0);
    S0 = __builtin_amdgcn_mfma_f32_16x16x32_bf16(kb0h, qfl, S0, 0,0,0);
    S0 = __builtin_amdgcn_mfma_f32_16x16x32_bf16(kb0h, qfh, S0, 0,0,0);
    S1 = __builtin_amdgcn_mfma_f32_16x16x32_bf16(kb1l, qfh, S1, 0,0,0);
    S1 = __builtin_amdgcn_mfma_f32_16x16x32_bf16(kb1h, qfl, S1, 0,0,0);
    S1 = __builtin_amdgcn_mfma_f32_16x16x32_bf16(kb1h, qfh, S1, 0,0,0);
    float tm = fmaxf(fmaxf(fmaxf(S0[0],S0[1]), fmaxf(S0[2],S0[3])),
                     fmaxf(fmaxf(S1[0],S1[1]), fmaxf(S1[2],S1[3])));
    tm = fmaxf(tm, __shfl_xor(tm, 16, 64));
    tm = fmaxf(tm, __shfl_xor(tm, 32, 64));
    float nm = fmaxf(m_s, tm);
    float alpha = expf(m_s - nm);
    m_s = nm;
    #pragma unroll
    for (int r=0;r<4;r++){
      float p0 = expf(S0[r] - nm);
      float p1 = expf(S1[r] - nm);
      short sh, sl2;
      split2s(p0, sh, sl2);
      Phw[ml*KSP + quad*4 + r] = sh;       Plw[ml*KSP + quad*4 + r] = sl2;
      split2s(p1, sh, sl2);
      Phw[ml*KSP + 16 + quad*4 + r] = sh;  Plw[ml*KSP + 16 + quad*4 + r] = sl2;
    }
    #pragma unroll
    for (int r=0;r<4;r++){
      float ar = __shfl(alpha, quad*4 + r, 16);
      O0[r] *= ar; O1[r] *= ar; Lacc[r] *= ar;
    }
    short8 pAh = *(const short8*)&Phw[ml*KSP + quad*8];
    short8 pAl = *(const short8*)&Plw[ml*KSP + quad*8];
    short8 vb0h = *(const short8*)&VhS[ml*KSP + quad*8];
    short8 vb0l = *(const short8*)&VlS[ml*KSP + quad*8];
    short8 vb1h = *(const short8*)&VhS[(16+ml)*KSP + quad*8];
    short8 vb1l = *(const short8*)&VlS[(16+ml)*KSP + quad*8];
    O0 = __builtin_amdgcn_mfma_f32_16x16x32_bf16(pAl, vb0h, O0, 0,0,0);
    O0 = __builtin_amdgcn_mfma_f32_16x16x32_bf16(pAh, vb0l, O0, 0,0,0);
    O0 = __builtin_amdgcn_mfma_f32_16x16x32_bf16(pAh, vb0h, O0, 0,0,0);
    O1 = __builtin_amdgcn_mfma_f32_16x16x32_bf16(pAl, vb1h, O1, 0,0,0);
    O1 = __builtin_amdgcn_mfma_f32_16x16x32_bf16(pAh, vb1l, O1, 0,0,0);
    O1 = __builtin_amdgcn_mfma_f32_16x16x32_bf16(pAh, vb1h, O1, 0,0,0);
    Lacc = __builtin_amdgcn_mfma_f32_16x16x32_bf16(pAh, ones, Lacc, 0,0,0);
    Lacc = __builtin_amdgcn_mfma_f32_16x16x32_bf16(pAl, ones, Lacc, 0,0,0);
  }
  #pragma unroll
  for (int r=0;r<4;r++){
    float inv = 1.f / Lacc[r];
    int row = (bb<<10) + q0 + quad*4 + r;
    __hip_bfloat16 hh, ll;
    split2(O0[r]*inv, hh, ll);
    aoh[row*256 + h*32 + ml] = hh;       aol[row*256 + h*32 + ml] = ll;
    split2(O1[r]*inv, hh, ll);
    aoh[row*256 + h*32 + 16 + ml] = hh;  aol[row*256 + h*32 + 16 + ml] = ll;
  }
}

// ---------------- concat queries into x[:, 256:512]
__global__ __launch_bounds__(256) void concat_kernel(
    const float* __restrict__ queries, float* __restrict__ x)
{
  int idx = blockIdx.x*256 + threadIdx.x;
  int d = idx & 255; int r = idx >> 8;
  x[(r<<9) + 256 + d] = queries[idx];
}

// ---------------- rmsnorm fp32 out
__global__ __launch_bounds__(256) void rmsnorm_kernel(
    const float* __restrict__ x, const float* __restrict__ g, float* __restrict__ y)
{
  int r = blockIdx.x; int tid = threadIdx.x;
  float v0 = x[(r<<9) + tid];
  float v1 = x[(r<<9) + 256 + tid];
  float ss = v0*v0 + v1*v1;
  #pragma unroll
  for (int off=32; off>0; off>>=1) ss += __shfl_down(ss, off, 64);
  __shared__ float wsum[4];
  if ((tid & 63) == 0) wsum[tid>>6] = ss;
  __syncthreads();
  float tot = wsum[0]+wsum[1]+wsum[2]+wsum[3];
  float scale = 22.62741699796952f / fmaxf(sqrtf(tot), 1e-12f);
  y[(r<<9) + tid]       = v0*scale*g[tid];
  y[(r<<9) + 256 + tid] = v1*scale*g[256+tid];
}

// ---------------- rmsnorm hi/lo out
__global__ __launch_bounds__(256) void rmsnorm_split_kernel(
    const float* __restrict__ x, const float* __restrict__ g,
    __hip_bfloat16* __restrict__ yh, __hip_bfloat16* __restrict__ yl)
{
  int r = blockIdx.x; int tid = threadIdx.x;
  float v0 = x[(r<<9) + tid];
  float v1 = x[(r<<9) + 256 + tid];
  float ss = v0*v0 + v1*v1;
  #pragma unroll
  for (int off=32; off>0; off>>=1) ss += __shfl_down(ss, off, 64);
  __shared__ float wsum[4];
  if ((tid & 63) == 0) wsum[tid>>6] = ss;
  __syncthreads();
  float tot = wsum[0]+wsum[1]+wsum[2]+wsum[3];
  float scale = 22.62741699796952f / fmaxf(sqrtf(tot), 1e-12f);
  float a = v0*scale*g[tid];
  float b = v1*scale*g[256+tid];
  __hip_bfloat16 h, l;
  split2(a, h, l); yh[(r<<9)+tid] = h;     yl[(r<<9)+tid] = l;
  split2(b, h, l); yh[(r<<9)+256+tid] = h; yl[(r<<9)+256+tid] = l;
}

// ---------------- rmsnorm bf16 out (ffa path)
__global__ __launch_bounds__(256) void rmsnorm_bf_kernel(
    const float* __restrict__ x, const float* __restrict__ g, __hip_bfloat16* __restrict__ y)
{
  int r = blockIdx.x; int tid = threadIdx.x;
  float v0 = x[(r<<9) + tid];
  float v1 = x[(r<<9) + 256 + tid];
  float ss = v0*v0 + v1*v1;
  #pragma unroll
  for (int off=32; off>0; off>>=1) ss += __shfl_down(ss, off, 64);
  __shared__ float wsum[4];
  if ((tid & 63) == 0) wsum[tid>>6] = ss;
  __syncthreads();
  float tot = wsum[0]+wsum[1]+wsum[2]+wsum[3];
  float scale = 22.62741699796952f / fmaxf(sqrtf(tot), 1e-12f);
  y[(r<<9) + tid]       = __float2bfloat16(v0*scale*g[tid]);
  y[(r<<9) + 256 + tid] = __float2bfloat16(v1*scale*g[256+tid]);
}

// ---------------- geglu glu: H fp32 padded [4096][2816] -> T hi/lo [4096][1408]
__global__ __launch_bounds__(256) void glu_split_kernel(
    const float* __restrict__ h, const float* __restrict__ mult,
    __hip_bfloat16* __restrict__ th, __hip_bfloat16* __restrict__ tl)
{
  int idx = blockIdx.x*256 + threadIdx.x;
  int r = idx / 1408; int j = idx - r*1408;
  float v = 0.f;
  if (j < 1365){
    float a  = h[(long)r*2816 + j];
    float gt = h[(long)r*2816 + 1408 + j];
    v = gelu_f(gt) * a * mult[j];
  }
  __hip_bfloat16 hh, ll; split2(v, hh, ll);
  th[idx] = hh; tl[idx] = ll;
}

// ---------------- geglu glu bf16 (ffa path)
__global__ __launch_bounds__(256) void glu_bf_kernel(
    const __hip_bfloat16* __restrict__ h, const float* __restrict__ mult,
    __hip_bfloat16* __restrict__ t)
{
  int idx = blockIdx.x*256 + threadIdx.x;
  int r = idx / 1408; int j = idx - r*1408;
  float v = 0.f;
  if (j < 1365){
    float a  = __bfloat162float(h[(long)r*2816 + j]);
    float gt = __bfloat162float(h[(long)r*2816 + 1408 + j]);
    v = gelu_f(gt) * a * mult[j];
  }
  t[idx] = __float2bfloat16(v);
}

// ---------------- split fp32 -> hi/lo
__global__ __launch_bounds__(256) void split32_kernel(
    const float* __restrict__ x, __hip_bfloat16* __restrict__ h, __hip_bfloat16* __restrict__ l)
{
  int idx = blockIdx.x*256 + threadIdx.x;
  float v = x[idx];
  __hip_bfloat16 hh, ll; split2(v, hh, ll);
  h[idx] = hh; l[idx] = ll;
}

// ---------------- MoE init
__global__ void moe_init_kernel(float* sum_raw, float* z_sum)
{
  int i = threadIdx.x;
  if (i < 64) sum_raw[i] = 0.f;
  if (i == 0) *z_sum = 0.f;
}

// ---------------- gating v2: 64 blocks x 64 tokens, LDS-aggregated atomics
// gate_w in LDS (stride 517 -> conflict-free over 16 expert lanes);
// 8-token passes; logit = 32-thread team (16 e x 2 halves) + 1 shfl_xor.
__global__ __launch_bounds__(256) void gating_kernel(
    const float* __restrict__ xn, const float* __restrict__ gate_w,
    int* __restrict__ idx1, int* __restrict__ idx2, int* __restrict__ route,
    float* __restrict__ gg1, float* __restrict__ gg2,
    float* __restrict__ sum_raw, float* __restrict__ z_sum)
{
  int t0 = blockIdx.x*64;
  int bb = t0 >> 10;
  int tid = threadIdx.x;
  __shared__ float wsm[16*517];    // 33.1 KB
  __shared__ float xs[8*516];      // 16.5 KB
  __shared__ float logits[8][17];
  __shared__ float lsum[16];
  __shared__ float lz;
  for (int i = tid; i < 8192; i += 256)
    wsm[(i>>9)*517 + (i & 511)] = gate_w[i];
  if (tid < 16) lsum[tid] = 0.f;
  if (tid == 0) lz = 0.f;
  __syncthreads();

  int team = tid >> 5;         // 0..7 (token within pass)
  int lane32 = tid & 31;
  int e = lane32 & 15, half = lane32 >> 4;

  for (int pass = 0; pass < 8; pass++){
    int tb = t0 + pass*8;
    // stage 8 token rows
    for (int i = tid; i < 4096; i += 256)
      xs[(i>>9)*516 + (i & 511)] = xn[((long)(tb + (i>>9))<<9) + (i & 511)];
    __syncthreads();
    const float* wr = &wsm[e*517 + half*256];
    const float* xr = &xs[team*516 + half*256];
    float acc = 0.f;
    #pragma unroll 8
    for (int d=0; d<256; d++) acc += xr[d]*wr[d];
    acc += __shfl_xor(acc, 16, 64);
    if (half == 0) logits[team][e] = acc;
    __syncthreads();
    if (tid < 8){
      int t = tb + tid;
      float r[16]; float mx = -1e30f;
      #pragma unroll
      for (int i=0;i<16;i++){ r[i] = logits[tid][i]; mx = fmaxf(mx, r[i]); }
      float sum = 0.f;
      #pragma unroll
      for (int i=0;i<16;i++){ r[i] = expf(r[i]-mx); sum += r[i]; }
      float lse = mx + logf(sum);
      atomicAdd(&lz, lse*lse);
      float inv = 1.f/sum;
      #pragma unroll
      for (int i=0;i<16;i++) r[i] *= inv;
      int i1 = -1; float b1 = -1.f;
      #pragma unroll
      for (int i=0;i<16;i++) if (r[i] > b1){ b1 = r[i]; i1 = i; }
      int i2 = -1; float b2 = -1.f;
      #pragma unroll
      for (int i=0;i<16;i++) if (i != i1 && r[i] > b2){ b2 = r[i]; i2 = i; }
      float s2 = fmaxf(b1 + b2, 1e-9f);
      float g1n = b1/s2, g2n = b2/s2;
      idx1[t] = i1; idx2[t] = i2;
      route[t] = (g2n > 0.2f) ? 1 : 0;
      gg1[t] = g1n; gg2[t] = g2n;
      #pragma unroll
      for (int i=0;i<16;i++) atomicAdd(&lsum[i], r[i]);
    }
    __syncthreads();
  }
  if (tid < 16) atomicAdd(&sum_raw[(bb<<4)+tid], lsum[tid]);
  if (tid == 0) atomicAdd(z_sum, lz);
}

// ---------------- capacity assignment: parallel segmented prefix scan
__global__ __launch_bounds__(256) void scan_kernel(
    const int* __restrict__ idx1, const int* __restrict__ idx2, const int* __restrict__ route,
    int* __restrict__ ts1, int* __restrict__ ts2, int* __restrict__ slot_token,
    int* __restrict__ count1)
{
  int bb = blockIdx.x >> 4;
  int e  = blockIdx.x & 15;
  int tid = threadIdx.x;
  int tbase = (bb<<10) + tid*4;
  int4 i1 = *(const int4*)&idx1[tbase];
  int4 i2 = *(const int4*)&idx2[tbase];
  int4 rt = *(const int4*)&route[tbase];
  int m1[4] = { i1.x==e, i1.y==e, i1.z==e, i1.w==e };
  int m2[4] = { i2.x==e, i2.y==e, i2.z==e, i2.w==e };
  int r4[4] = { rt.x, rt.y, rt.z, rt.w };
  int c1 = m1[0]+m1[1]+m1[2]+m1[3];
  int c2 = (m2[0]&&r4[0]) + (m2[1]&&r4[1]) + (m2[2]&&r4[2]) + (m2[3]&&r4[3]);
  __shared__ int s1[256], s2v[256];
  s1[tid] = c1; s2v[tid] = c2;
  __syncthreads();
  for (int off=1; off<256; off<<=1){
    int v1 = (tid>=off) ? s1[tid-off] : 0;
    int v2 = (tid>=off) ? s2v[tid-off] : 0;
    __syncthreads();
    s1[tid] += v1; s2v[tid] += v2;
    __syncthreads();
  }
  int tot1 = s1[255], tot2 = s2v[255];
  int p1 = s1[tid] - c1;
  int p2 = s2v[tid] - c2;
  if (tid == 0) count1[(bb<<4)+e] = tot1;
  int base = ((e<<2)+bb)*CAPN;
  #pragma unroll
  for (int i=0;i<4;i++){
    int t = tbase + i;
    if (m1[i]){
      if (p1 < CAPN){ ts1[t] = base+p1; slot_token[base+p1] = t; }
      else ts1[t] = -1;
      p1++;
    }
    if (m2[i]){
      if (r4[i]){
        int pos = tot1 + p2;
        if (pos < CAPN){ ts2[t] = base+pos; slot_token[base+pos] = t; }
        else ts2[t] = -1;
        p2++;
      } else ts2[t] = -1;
    }
  }
  int filled = min(CAPN, tot1 + tot2);
  if (tid < CAPN && tid >= filled) slot_token[base+tid] = -1;
}

// ---------------- gather + layernorm -> xin bf16
__global__ __launch_bounds__(256) void gather_ln_kernel(
    const float* __restrict__ xn, const int* __restrict__ slot_token,
    const float* __restrict__ ln_g, const float* __restrict__ ln_b,
    __hip_bfloat16* __restrict__ xin)
{
  int s = blockIdx.x; int tid = threadIdx.x;
  int t = slot_token[s];
  int e = s >> 9;
  if (t < 0){
    xin[(s<<9)+tid] = __float2bfloat16(0.f);
    xin[(s<<9)+256+tid] = __float2bfloat16(0.f);
    return;
  }
  float v0 = xn[(t<<9)+tid];
  float v1 = xn[(t<<9)+256+tid];
  float sm = v0+v1, sq = v0*v0+v1*v1;
  #pragma unroll
  for (int off=32; off>0; off>>=1){
    sm += __shfl_down(sm, off, 64);
    sq += __shfl_down(sq, off, 64);
  }
  __shared__ float s1[4], s2buf[4];
  if ((tid & 63) == 0){ s1[tid>>6] = sm; s2buf[tid>>6] = sq; }
  __syncthreads();
  float tsm = s1[0]+s1[1]+s1[2]+s1[3];
  float tsq = s2buf[0]+s2buf[1]+s2buf[2]+s2buf[3];
  float mean = tsm * (1.f/512.f);
  float var = tsq * (1.f/512.f) - mean*mean;
  float rstd = rsqrtf(var + 1e-5f);
  xin[(s<<9)+tid]     = __float2bfloat16((v0-mean)*rstd*ln_g[(e<<9)+tid]     + ln_b[(e<<9)+tid]);
  xin[(s<<9)+256+tid] = __float2bfloat16((v1-mean)*rstd*ln_g[(e<<9)+256+tid] + ln_b[(e<<9)+256+tid]);
}

// ---------------- combine (in-place)
__global__ __launch_bounds__(256) void combine_kernel(
    float* __restrict__ x, const float* __restrict__ h2,
    const int* __restrict__ ts1, const int* __restrict__ ts2,
    const float* __restrict__ gg1, const float* __restrict__ gg2)
{
  int idx = blockIdx.x*256 + threadIdx.x;
  int t = idx >> 9; int d = idx & 511;
  float v = x[idx];
  int s1 = ts1[t]; if (s1 >= 0) v += gg1[t]*h2[(s1<<9)+d];
  int s2 = ts2[t]; if (s2 >= 0) v += gg2[t]*h2[(s2<<9)+d];
  x[idx] = v;
}

// ---------------- aux losses
__global__ void aux_kernel(
    const float* __restrict__ sum_raw, const int* __restrict__ count1,
    const float* __restrict__ z_sum, float* __restrict__ out)
{
  int tid = threadIdx.x;
  float v = (sum_raw[tid] * (1.f/1024.f)) * ((float)count1[tid] * (1.f/1024.f));
  #pragma unroll
  for (int off=32; off>0; off>>=1) v += __shfl_down(v, off, 64);
  if (tid == 0){
    float bal = v * (1.f/64.f) * 256.f * 0.01f;
    float zl = (*z_sum) * (1.f/4096.f) * 0.001f;
    out[0] = bal + zl;
    out[1] = bal;
    out[2] = zl;
  }
}

extern "C" void kernel_launch(void* const* d_in, const int* in_sizes, int n_in,
                              void* d_out, int out_size, void* d_ws, size_t ws_size,
                              hipStream_t stream)
{
  const float* K_in   = (const float*)d_in[0];
  const float* V_in   = (const float*)d_in[1];
  const float* Q_in   = (const float*)d_in[2];
  const float* w_topo = (const float*)d_in[3];
  const float* b_topo = (const float*)d_in[4];
  const float* w_val  = (const float*)d_in[5];
  const float* b_val  = (const float*)d_in[6];
  const float* wq     = (const float*)d_in[7];
  const float* bq     = (const float*)d_in[8];
  const float* wk     = (const float*)d_in[9];
  const float* bk     = (const float*)d_in[10];
  const float* wv     = (const float*)d_in[11];
  const float* bv     = (const float*)d_in[12];
  const float* wo     = (const float*)d_in[13];
  const float* bo     = (const float*)d_in[14];
  const float* ffb_g  = (const float*)d_in[15];
  const float* ffb_w1 = (const float*)d_in[16];
  const float* ffb_b1 = (const float*)d_in[17];
  const float* ffb_mult=(const float*)d_in[18];
  const float* ffb_w2 = (const float*)d_in[19];
  const float* ffb_b2 = (const float*)d_in[20];
  const float* prenorm_g=(const float*)d_in[21];
  const float* gate_w = (const float*)d_in[22];
  const float* exp_ln_g=(const float*)d_in[23];
  const float* exp_ln_b=(const float*)d_in[24];
  const float* exp_w1 = (const float*)d_in[25];
  const float* exp_b1 = (const float*)d_in[26];
  const float* exp_w2 = (const float*)d_in[27];
  const float* exp_b2 = (const float*)d_in[28];
  const float* ffa_g  = (const float*)d_in[29];
  const float* ffa_w1 = (const float*)d_in[30];
  const float* ffa_b1 = (const float*)d_in[31];
  const float* ffa_mult=(const float*)d_in[32];
  const float* ffa_w2 = (const float*)d_in[33];
  const float* ffa_b2 = (const float*)d_in[34];
  const float* w_out  = (const float*)d_in[35];
  const float* b_out  = (const float*)d_in[36];
  float* dout = (float*)d_out;

  float* wsf = (float*)d_ws;
  int*   wsi = (int*)d_ws;

  // ---- layout (float offsets) ----
  const size_t A0 = 0;
  const size_t B0 = 11534336;
  const size_t OXA = 17301504;
  const size_t OXB = 19398656;
  const size_t OWP = 21495808;
  const size_t OMI = 21889024;

  __hip_bfloat16* qhi = (__hip_bfloat16*)(wsf + A0);
  __hip_bfloat16* khi = (__hip_bfloat16*)(wsf + A0 + 524288);
  __hip_bfloat16* vhi = (__hip_bfloat16*)(wsf + A0 + 1048576);
  __hip_bfloat16* qlo = (__hip_bfloat16*)(wsf + A0 + 1572864);
  __hip_bfloat16* klo = (__hip_bfloat16*)(wsf + A0 + 2097152);
  __hip_bfloat16* vlo = (__hip_bfloat16*)(wsf + A0 + 2621440);
  float* QP = wsf + A0 + 3145728;
  __hip_bfloat16* aohi = (__hip_bfloat16*)(wsf + A0 + 6291456);
  __hip_bfloat16* aolo = (__hip_bfloat16*)(wsf + A0 + 6815744);
  __hip_bfloat16* qsh = (__hip_bfloat16*)(wsf + A0);
  __hip_bfloat16* qsl = (__hip_bfloat16*)(wsf + A0 + 524288);
  __hip_bfloat16* ksh = (__hip_bfloat16*)(wsf + A0 + 1048576);
  __hip_bfloat16* ksl = (__hip_bfloat16*)(wsf + A0 + 1572864);
  __hip_bfloat16* vth = (__hip_bfloat16*)(wsf + A0 + 2097152);
  __hip_bfloat16* vtl = (__hip_bfloat16*)(wsf + A0 + 2621440);
  float* QF = wsf + B0 + 262144;
  float* Hb = wsf + A0;
  __hip_bfloat16* yh   = (__hip_bfloat16*)(wsf + B0);
  __hip_bfloat16* yl   = (__hip_bfloat16*)(wsf + B0 + 1048576);
  __hip_bfloat16* fw1h = (__hip_bfloat16*)(wsf + B0 + 2097152);
  __hip_bfloat16* fw1l = fw1h + 1441792;
  __hip_bfloat16* th   = (__hip_bfloat16*)(wsf + B0);
  __hip_bfloat16* tl   = (__hip_bfloat16*)(wsf + B0 + 2883584);
  __hip_bfloat16* fw2h = (__hip_bfloat16*)(wsf + A0);
  __hip_bfloat16* fw2l = fw2h + 720896;
  float* Pffb = wsf + A0 + 1048576;
  __hip_bfloat16* wte   = (__hip_bfloat16*)(wsf + A0);
  __hip_bfloat16* xin_bf= (__hip_bfloat16*)(wsf + A0 + 5767168);
  __hip_bfloat16* h1_bf = (__hip_bfloat16*)(wsf + A0 + 7864320);
  float* H2 = wsf + 13631488;
  float* YM = wsf + B0;
  __hip_bfloat16* y_bf = (__hip_bfloat16*)(wsf + A0);
  __hip_bfloat16* wf1  = (__hip_bfloat16*)(wsf + A0 + 1048576);
  __hip_bfloat16* h_bf = (__hip_bfloat16*)(wsf + A0 + 1769472);
  __hip_bfloat16* t_bf = (__hip_bfloat16*)(wsf + A0 + 7536640);
  __hip_bfloat16* wf2  = (__hip_bfloat16*)(wsf + A0 + 10420224);
  float* Pffa = wsf + B0;
  __hip_bfloat16* xah = (__hip_bfloat16*)(wsf + A0);
  __hip_bfloat16* xal = (__hip_bfloat16*)(wsf + A0 + 1048576);
  float* Pout = wsf + A0 + 2097152;
  __hip_bfloat16* wp = (__hip_bfloat16*)(wsf + OWP);
  __hip_bfloat16* wqh = wp;            __hip_bfloat16* wkh = wp + 65536;
  __hip_bfloat16* wvh = wp + 131072;   __hip_bfloat16* wql = wp + 196608;
  __hip_bfloat16* wkl = wp + 262144;   __hip_bfloat16* wvl = wp + 327680;
  __hip_bfloat16* woh = wp + 393216;   __hip_bfloat16* wol = wp + 458752;
  __hip_bfloat16* wouth = wp + 524288; __hip_bfloat16* woutl = wp + 655360;

  int* idx1 = wsi + OMI + 0;
  int* idx2 = wsi + OMI + 4096;
  int* route= wsi + OMI + 8192;
  int* ts1  = wsi + OMI + 12288;
  int* ts2  = wsi + OMI + 16384;
  int* slot_token = wsi + OMI + 20480;
  int* count1     = wsi + OMI + 28672;
  float* sum_raw  = wsf + OMI + 28736;
  float* z_sum    = wsf + OMI + 28800;
  float* gg1      = wsf + OMI + 28864;
  float* gg2      = wsf + OMI + 32960;
  float* bias_qkv = wsf + OMI + 37056;

  // ---- phase 0: static weight conversions ----
  convT2_kernel<<<dim3(4,4),  256, 0, stream>>>(wq, 256, 256, wqh, wql, 256, 256, 0, 0);
  convT2_kernel<<<dim3(4,4),  256, 0, stream>>>(wk, 256, 256, wkh, wkl, 256, 256, 0, 0);
  convT2_kernel<<<dim3(4,4),  256, 0, stream>>>(wv, 256, 256, wvh, wvl, 256, 256, 0, 0);
  convT2_kernel<<<dim3(4,4),  256, 0, stream>>>(wo, 256, 256, woh, wol, 256, 256, 0, 0);
  convT2_kernel<<<dim3(4,8),  256, 0, stream>>>(w_out, 256, 512, wouth, woutl, 256, 512, 0, 0);
  convT2_kernel<<<dim3(44,8), 256, 0, stream>>>(ffb_w1, 2730, 512, fw1h, fw1l, 2816, 512, 1365, 1408);
  pack_bias_kernel<<<3, 256, 0, stream>>>(bq, bk, bv, bias_qkv);

  // ---- phase 1: topo / values ----
  topo_kernel<<<8192, 256, 0, stream>>>(K_in, Q_in, w_topo, b_topo, khi, klo, qhi, qlo, QF);
  values_kernel<<<4096, 256, 0, stream>>>(V_in, w_val, b_val, vhi, vlo);

  // ---- phase 2: QKV projections ----
  sgemm_kernel<<<dim3(2,32,3), 256, 0, stream>>>(
      qhi, qlo, 256, 1048576, wqh, wql, 256, 65536,
      bias_qkv, 256, 0, 0, 256, nullptr, 0, QP, 256, 1048576, 256, 0,
      nullptr, 0, 1);

  // ---- phase 3: MFMA flash attention ----
  qksplit_kernel<<<4096, 256, 0, stream>>>(QP, qsh, qsl, ksh, ksl);
  vtrans_kernel<<<dim3(16,32), 256, 0, stream>>>(QP + 2097152, vth, vtl);
  attn_mfma_kernel<<<dim3(16,32), 256, 0, stream>>>(qsh, qsl, ksh, ksl, vth, vtl, aohi, aolo);

  // ---- phase 4: o-proj + concat ----
  sgemm_kernel<<<dim3(2,32,1), 256, 0, stream>>>(
      aohi, aolo, 256, 0, woh, wol, 256, 0,
      bo, 256, 0, 0, 0, nullptr, 0, wsf+OXA, 512, 0, 256, 0,
      nullptr, 0, 1);
  concat_kernel<<<4096, 256, 0, stream>>>(QF, wsf+OXA);

  // ---- phase 5: ffb geglu ----
  rmsnorm_split_kernel<<<4096, 256, 0, stream>>>(wsf+OXA, ffb_g, yh, yl);
  sgemm_kernel<<<dim3(22,32,1), 256, 0, stream>>>(
      yh, yl, 512, 0, fw1h, fw1l, 512, 0,
      ffb_b1, 2730, 1365, 1408, 0, nullptr, 0, Hb, 2816, 0, 512, 0,
      nullptr, 0, 1);
  glu_split_kernel<<<22528, 256, 0, stream>>>(Hb, ffb_mult, th, tl);
  convT2_kernel<<<dim3(8,22), 256, 0, stream>>>(ffb_w2, 512, 1365, fw2h, fw2l, 512, 1408, 0, 0);
  sgemm_kernel<<<dim3(4,32,4), 256, 0, stream>>>(
      th, tl, 1408, 0, fw2h, fw2l, 1408, 0,
      nullptr, 0, 0, 0, 0, nullptr, 0, nullptr, 512, 0, 1408, 0,
      Pffb, 2097152, 4);
  reduce_kernel<<<8192, 256, 0, stream>>>(
      Pffb, 2097152, 4, ffb_b2, wsf+OXA, wsf+OXB, 511, 9, 512, 0, 2097152);

  // ---- phase 6: MoE ----
  rmsnorm_kernel<<<4096, 256, 0, stream>>>(wsf+OXB, prenorm_g, YM);
  moe_init_kernel<<<1, 64, 0, stream>>>(sum_raw, z_sum);
  gating_kernel<<<64, 256, 0, stream>>>(YM, gate_w, idx1, idx2, route, gg1, gg2, sum_raw, z_sum);
  scan_kernel<<<64, 256, 0, stream>>>(idx1, idx2, route, ts1, ts2, slot_token, count1);
  gather_ln_kernel<<<8192, 256, 0, stream>>>(YM, slot_token, exp_ln_g, exp_ln_b, xin_bf);
  convT_kernel<<<dim3(22, 8, 16), 256, 0, stream>>>(exp_w1, 1365, 512, (long)512*1365,
                                                    wte, 1408, 512, (long)1408*512, 0, 0);
  bgemm_kernel<<<dim3(11,4,16), 256, 0, stream>>>(
      xin_bf, 512, (long)512*512, wte, 512, (long)1408*512,
      exp_b1, 1365, 0, 0, 1365, nullptr, 0, 0,
      h1_bf, 1408, (long)512*1408, 1, 512, 2,
      nullptr, 0, 1);
  convT_kernel<<<dim3(8, 22, 16), 256, 0, stream>>>(exp_w2, 512, 1365, (long)1365*512,
                                                    wte, 512, 1408, (long)512*1408, 0, 0);
  bgemm_kernel<<<dim3(4,4,16), 256, 0, stream>>>(
      h1_bf, 1408, (long)512*1408, wte, 1408, (long)512*1408,
      exp_b2, 512, 0, 0, 512, nullptr, 0, 0,
      H2, 512, (long)512*512, 0, 1408, 0,
      nullptr, 0, 1);
  combine_kernel<<<8192, 256, 0, stream>>>(wsf+OXB, H2, ts1, ts2, gg1, gg2);
  aux_kernel<<<1, 64, 0, stream>>>(sum_raw, count1, z_sum, dout + 4096*256);

  // ---- phase 7: ffa geglu ----
  rmsnorm_bf_kernel<<<4096, 256, 0, stream>>>(wsf+OXB, ffa_g, y_bf);
  convT_kernel<<<dim3(44, 8, 1), 256, 0, stream>>>(ffa_w1, 2730, 512, 0,
                                                   wf1, 2816, 512, 0, 1365, 1408);
  bgemm_kernel<<<dim3(22,32,1), 256, 0, stream>>>(
      y_bf, 512, 0, wf1, 512, 0,
      ffa_b1, 2730, 1365, 1408, 0, nullptr, 0, 0,
      h_bf, 2816, 0, 1, 512, 0,
      nullptr, 0, 1);
  glu_bf_kernel<<<22528, 256, 0, stream>>>(h_bf, ffa_mult, t_bf);
  convT_kernel<<<dim3(8, 22, 1), 256, 0, stream>>>(ffa_w2, 512, 1365, 0,
                                                   wf2, 512, 1408, 0, 0, 0);
  bgemm_kernel<<<dim3(4,32,2), 256, 0, stream>>>(
      t_bf, 1408, 0, wf2, 1408, 0,
      nullptr, 0, 0, 0, 0, nullptr, 0, 0,
      nullptr, 512, 0, 0, 1408, 0,
      Pffa, 2097152, 2);
  reduce_kernel<<<8192, 256, 0, stream>>>(
      Pffa, 2097152, 2, ffa_b2, wsf+OXB, wsf+OXA, 511, 9, 512, 0, 2097152);

  // ---- phase 8: out = gelu(XA @ w_out + b_out), split-K=4 ----
  split32_kernel<<<8192, 256, 0, stream>>>(wsf+OXA, xah, xal);
  sgemm_kernel<<<dim3(2,32,4), 256, 0, stream>>>(
      xah, xal, 512, 0, wouth, woutl, 512, 0,
      nullptr, 0, 0, 0, 0, nullptr, 0, nullptr, 256, 0, 512, 0,
      Pout, 1048576, 4);
  reduce_kernel<<<4096, 256, 0, stream>>>(
      Pout, 1048576, 4, b_out, nullptr, dout, 255, 8, 256, 1, 1048576);
}

// Round 11
// 804.766 us; speedup vs baseline: 1.0608x; 1.0608x over previous
//
#include <hip/hip_runtime.h>
#include <hip/hip_bf16.h>
#include <math.h>

// B=4 S=1024 DM=256 H=8 HD=32 CIN=23 E=16 D2=512 HE=1365 2HE=2730 CAP=128
#define CAPN 128

typedef short short8 __attribute__((ext_vector_type(8)));
typedef short short4v __attribute__((ext_vector_type(4)));
typedef float f32x4 __attribute__((ext_vector_type(4)));

__device__ __forceinline__ float gelu_f(float x){
  return 0.5f*x*(1.0f+erff(x*0.7071067811865476f));
}
__device__ __forceinline__ void split2(float v, __hip_bfloat16& h, __hip_bfloat16& l){
  h = __float2bfloat16(v);
  l = __float2bfloat16(v - __bfloat162float(h));
}
__device__ __forceinline__ void split2s(float v, short& h, short& l){
  __hip_bfloat16 hh = __float2bfloat16(v);
  __hip_bfloat16 ll = __float2bfloat16(v - __bfloat162float(hh));
  h = *(short*)&hh; l = *(short*)&ll;
}

// ---------------- topo
__global__ __launch_bounds__(256) void topo_kernel(
    const float* __restrict__ K, const float* __restrict__ Q,
    const float* __restrict__ w, const float* __restrict__ b,
    __hip_bfloat16* __restrict__ khi, __hip_bfloat16* __restrict__ klo,
    __hip_bfloat16* __restrict__ qhi, __hip_bfloat16* __restrict__ qlo,
    float* __restrict__ qf32)
{
  int idx = blockIdx.x*256 + threadIdx.x;   // 2M
  int d = idx & 255;
  int r = idx >> 8;
  int bb = r >> 11;
  int n  = r & 2047;
  const float* src = (n < 1024) ? (K + ((bb<<10) + n)*3)
                                : (Q + ((bb<<10) + (n-1024))*3);
  float v = b[d] + src[0]*w[d] + src[1]*w[256+d] + src[2]*w[512+d];
  v = gelu_f(v);
  int off = (((bb<<10) + (n & 1023))<<8) + d;
  __hip_bfloat16 h, l; split2(v, h, l);
  if (n < 1024){ khi[off] = h; klo[off] = l; }
  else         { qhi[off] = h; qlo[off] = l; qf32[off] = v; }
}

// ---------------- values
__global__ __launch_bounds__(256) void values_kernel(
    const float* __restrict__ V, const float* __restrict__ w,
    const float* __restrict__ b,
    __hip_bfloat16* __restrict__ vhi, __hip_bfloat16* __restrict__ vlo)
{
  int idx = blockIdx.x*256 + threadIdx.x;
  int d = idx & 255; int r = idx >> 8;
  const float* src = V + r*23;
  float acc = b[d];
  #pragma unroll
  for (int c=0;c<23;c++) acc += src[c]*w[c*256+d];
  acc = gelu_f(acc);
  __hip_bfloat16 h, l; split2(acc, h, l);
  vhi[idx] = h; vlo[idx] = l;
}

// ---------------- split-bf16 "fp32" MFMA GEMM (pipelined, optional split-K)
#define SLP 40
__global__ __launch_bounds__(256) void sgemm_kernel(
    const __hip_bfloat16* __restrict__ Ah_, const __hip_bfloat16* __restrict__ Al_,
    int lda, long sA,
    const __hip_bfloat16* __restrict__ Wh_, const __hip_bfloat16* __restrict__ Wl_,
    int ldw, long sW,
    const float* __restrict__ bias, int nbias, int bsplit, int bsplitPad, long sB,
    const float* __restrict__ R, int ldr,
    float* __restrict__ C, int ldc, long sC,
    int K, int act,
    float* __restrict__ P, long pz, int splitK)
{
  int z = blockIdx.z / splitK;
  int kc = blockIdx.z - z*splitK;
  const short* Ah = (const short*)Ah_ + (long)z*sA;
  const short* Al = (const short*)Al_ + (long)z*sA;
  const short* Wh = (const short*)Wh_ + (long)z*sW;
  const short* Wl = (const short*)Wl_ + (long)z*sW;
  int bm = blockIdx.y*128, bn = blockIdx.x*128;
  int tid = threadIdx.x, lane = tid & 63, wave = tid >> 6;
  int wm = (wave & 1)*64, wn = (wave >> 1)*64;

  __shared__ short AsH[128*SLP], AsL[128*SLP], BsH[128*SLP], BsL[128*SLP];

  f32x4 acc[4][4];
  f32x4 zero4 = {0.f,0.f,0.f,0.f};
  #pragma unroll
  for (int i=0;i<4;i++)
    #pragma unroll
    for (int j=0;j<4;j++) acc[i][j] = zero4;

  int srow = tid >> 1, scol = (tid & 1)*16;
  int ml = lane & 15, q = lane >> 4;
  long abase = (long)(bm+srow)*lda + scol;
  long bbase = (long)(bn+srow)*ldw + scol;

  int Kc = K / splitK;
  int kbeg = kc * Kc, kend = kbeg + Kc;

  short8 ah0 = *(const short8*)&Ah[abase + kbeg];
  short8 ah1 = *(const short8*)&Ah[abase + kbeg + 8];
  short8 al0 = *(const short8*)&Al[abase + kbeg];
  short8 al1 = *(const short8*)&Al[abase + kbeg + 8];
  short8 bh0 = *(const short8*)&Wh[bbase + kbeg];
  short8 bh1 = *(const short8*)&Wh[bbase + kbeg + 8];
  short8 bl0 = *(const short8*)&Wl[bbase + kbeg];
  short8 bl1 = *(const short8*)&Wl[bbase + kbeg + 8];

  for (int k0 = kbeg; k0 < kend; k0 += 32){
    __syncthreads();
    *(short8*)&AsH[srow*SLP + scol]     = ah0;
    *(short8*)&AsH[srow*SLP + scol + 8] = ah1;
    *(short8*)&AsL[srow*SLP + scol]     = al0;
    *(short8*)&AsL[srow*SLP + scol + 8] = al1;
    *(short8*)&BsH[srow*SLP + scol]     = bh0;
    *(short8*)&BsH[srow*SLP + scol + 8] = bh1;
    *(short8*)&BsL[srow*SLP + scol]     = bl0;
    *(short8*)&BsL[srow*SLP + scol + 8] = bl1;
    __syncthreads();
    if (k0 + 32 < kend){
      long ab = abase + k0 + 32;
      long bb2 = bbase + k0 + 32;
      ah0 = *(const short8*)&Ah[ab];
      ah1 = *(const short8*)&Ah[ab + 8];
      al0 = *(const short8*)&Al[ab];
      al1 = *(const short8*)&Al[ab + 8];
      bh0 = *(const short8*)&Wh[bb2];
      bh1 = *(const short8*)&Wh[bb2 + 8];
      bl0 = *(const short8*)&Wl[bb2];
      bl1 = *(const short8*)&Wl[bb2 + 8];
    }
    short8 afh[4], afl[4], bfh[4], bfl[4];
    #pragma unroll
    for (int i=0;i<4;i++){
      afh[i] = *(const short8*)&AsH[(wm + 16*i + ml)*SLP + q*8];
      afl[i] = *(const short8*)&AsL[(wm + 16*i + ml)*SLP + q*8];
    }
    #pragma unroll
    for (int j=0;j<4;j++){
      bfh[j] = *(const short8*)&BsH[(wn + 16*j + ml)*SLP + q*8];
      bfl[j] = *(const short8*)&BsL[(wn + 16*j + ml)*SLP + q*8];
    }
    #pragma unroll
    for (int i=0;i<4;i++)
      #pragma unroll
      for (int j=0;j<4;j++){
        acc[i][j] = __builtin_amdgcn_mfma_f32_16x16x32_bf16(afh[i], bfh[j], acc[i][j], 0,0,0);
        acc[i][j] = __builtin_amdgcn_mfma_f32_16x16x32_bf16(afh[i], bfl[j], acc[i][j], 0,0,0);
        acc[i][j] = __builtin_amdgcn_mfma_f32_16x16x32_bf16(afl[i], bfh[j], acc[i][j], 0,0,0);
      }
  }

  if (P){   // raw partial store (split-K path)
    float* Pb = P + (long)blockIdx.z * pz;
    #pragma unroll
    for (int i=0;i<4;i++)
      #pragma unroll
      for (int r=0;r<4;r++){
        int gm = bm + wm + 16*i + q*4 + r;
        #pragma unroll
        for (int j=0;j<4;j++){
          int gn = bn + wn + 16*j + ml;
          Pb[(long)gm*ldc + gn] = acc[i][j][r];
        }
      }
    return;
  }

  const float* biasz = bias ? bias + (long)z*sB : nullptr;
  long coff = (long)z*sC;
  #pragma unroll
  for (int i=0;i<4;i++){
    #pragma unroll
    for (int r=0;r<4;r++){
      int gm = bm + wm + 16*i + q*4 + r;
      #pragma unroll
      for (int j=0;j<4;j++){
        int gn = bn + wn + 16*j + ml;
        float v = acc[i][j][r];
        if (biasz){
          int bi;
          if (bsplit){
            if (gn < bsplit) bi = gn;
            else if (gn >= bsplitPad && gn < bsplitPad + (nbias - bsplit)) bi = gn - (bsplitPad - bsplit);
            else bi = -1;
          } else bi = (gn < nbias) ? gn : -1;
          if (bi >= 0) v += biasz[bi];
        }
        if (act == 1) v = gelu_f(v);
        if (R) v += R[(long)gm*ldr + gn];
        C[coff + (long)gm*ldc + gn] = v;
      }
    }
  }
}

// ---------------- pure-bf16 MFMA GEMM (pipelined, optional split-K)
#define LP 56
__global__ __launch_bounds__(256) void bgemm_kernel(
    const __hip_bfloat16* __restrict__ A, int lda, long sA,
    const __hip_bfloat16* __restrict__ WT, int ldw, long sW,
    const float* __restrict__ bias, int nbias, int bsplit, int bsplitPad, long sB,
    const float* __restrict__ R, int ldr, long sR,
    void* __restrict__ C, int ldc, long sC, int cIsBf16,
    int K, int act,
    float* __restrict__ P, long pz, int splitK)
{
  int z = blockIdx.z / splitK;
  int kc = blockIdx.z - z*splitK;
  const short* Ab = (const short*)A + (long)z*sA;
  const short* Bb = (const short*)WT + (long)z*sW;
  int bm = blockIdx.y*128, bn = blockIdx.x*128;
  int tid = threadIdx.x, lane = tid & 63, wave = tid >> 6;
  int wm = (wave & 1)*64, wn = (wave >> 1)*64;

  __shared__ short As[128*LP];
  __shared__ short Bs[128*LP];

  f32x4 acc[4][4];
  f32x4 zero4 = {0.f,0.f,0.f,0.f};
  #pragma unroll
  for (int i=0;i<4;i++)
    #pragma unroll
    for (int j=0;j<4;j++) acc[i][j] = zero4;

  int g0 = tid, g1 = tid + 256;
  int r0 = g0 >> 2, c0 = (g0 & 3) * 8;
  int r1 = g1 >> 2, c1 = (g1 & 3) * 8;
  int ml = lane & 15, q = lane >> 4;
  long a0base = (long)(bm+r0)*lda + c0;
  long a1base = (long)(bm+r1)*lda + c1;
  long b0base = (long)(bn+r0)*ldw + c0;
  long b1base = (long)(bn+r1)*ldw + c1;

  int Kc = K / splitK;
  int kbeg = kc * Kc, kend = kbeg + Kc;

  short8 av0 = *(const short8*)&Ab[a0base + kbeg];
  short8 av1 = *(const short8*)&Ab[a1base + kbeg];
  short8 bv0 = *(const short8*)&Bb[b0base + kbeg];
  short8 bv1 = *(const short8*)&Bb[b1base + kbeg];

  for (int k0 = kbeg; k0 < kend; k0 += 32){
    __syncthreads();
    *(short8*)&As[r0*LP + c0] = av0;
    *(short8*)&As[r1*LP + c1] = av1;
    *(short8*)&Bs[r0*LP + c0] = bv0;
    *(short8*)&Bs[r1*LP + c1] = bv1;
    __syncthreads();
    if (k0 + 32 < kend){
      av0 = *(const short8*)&Ab[a0base + k0 + 32];
      av1 = *(const short8*)&Ab[a1base + k0 + 32];
      bv0 = *(const short8*)&Bb[b0base + k0 + 32];
      bv1 = *(const short8*)&Bb[b1base + k0 + 32];
    }
    short8 af[4], bfv[4];
    #pragma unroll
    for (int i=0;i<4;i++) af[i]  = *(const short8*)&As[(wm + 16*i + ml)*LP + q*8];
    #pragma unroll
    for (int j=0;j<4;j++) bfv[j] = *(const short8*)&Bs[(wn + 16*j + ml)*LP + q*8];
    #pragma unroll
    for (int i=0;i<4;i++)
      #pragma unroll
      for (int j=0;j<4;j++)
        acc[i][j] = __builtin_amdgcn_mfma_f32_16x16x32_bf16(af[i], bfv[j], acc[i][j], 0,0,0);
  }

  if (P){
    float* Pb = P + (long)blockIdx.z * pz;
    #pragma unroll
    for (int i=0;i<4;i++)
      #pragma unroll
      for (int r=0;r<4;r++){
        int gm = bm + wm + 16*i + q*4 + r;
        #pragma unroll
        for (int j=0;j<4;j++){
          int gn = bn + wn + 16*j + ml;
          Pb[(long)gm*ldc + gn] = acc[i][j][r];
        }
      }
    return;
  }

  const float* biasz = bias ? bias + (long)z*sB : nullptr;
  const float* Rz = R ? R + (long)z*sR : nullptr;
  long coff = (long)z*sC;
  #pragma unroll
  for (int i=0;i<4;i++){
    #pragma unroll
    for (int r=0;r<4;r++){
      int gm = bm + wm + 16*i + q*4 + r;
      #pragma unroll
      for (int j=0;j<4;j++){
        int gn = bn + wn + 16*j + ml;
        float v = acc[i][j][r];
        if (biasz){
          int bi;
          if (bsplit){
            if (gn < bsplit) bi = gn;
            else if (gn >= bsplitPad && gn < bsplitPad + (nbias - bsplit)) bi = gn - (bsplitPad - bsplit);
            else bi = -1;
          } else bi = (gn < nbias) ? gn : -1;
          if (bi >= 0) v += biasz[bi];
        }
        if (act == 2) v = (v > 0.f) ? v : 0.01f*v;
        if (Rz) v += Rz[(long)gm*ldr + gn];
        if (cIsBf16) ((__hip_bfloat16*)C)[coff + (long)gm*ldc + gn] = __float2bfloat16(v);
        else         ((float*)C)[coff + (long)gm*ldc + gn] = v;
      }
    }
  }
}

// ---------------- split-K reduce
__global__ __launch_bounds__(256) void reduce_kernel(
    const float* __restrict__ P, long zStride, int nsplit,
    const float* __restrict__ bias,
    const float* __restrict__ R, float* __restrict__ out,
    int Nmask, int logN, int ldOut, int act, long total)
{
  long idx = (long)blockIdx.x*256 + threadIdx.x;
  if (idx >= total) return;
  long zz = idx / zStride;
  long rem = idx - zz*zStride;
  const float* Pb = P + zz*(long)nsplit*zStride + rem;
  float v = 0.f;
  for (int k=0;k<nsplit;k++) v += Pb[(long)k*zStride];
  int n = (int)(idx & Nmask);
  long row = idx >> logN;
  if (bias) v += bias[n];
  if (act == 1) v = gelu_f(v);
  long o = row*(long)ldOut + n;
  if (R) v += R[o];
  out[o] = v;
}

// ---------------- weight transpose+convert (single bf16 out, z-batched)
__global__ __launch_bounds__(256) void convT_kernel(
    const float* __restrict__ W, int N, int K, long sW,
    __hip_bfloat16* __restrict__ out, int Npad, int Kpad, long sO,
    int split, int splitPad)
{
  int z = blockIdx.z;
  int n0 = blockIdx.x*64, k0 = blockIdx.y*64;
  int tid = threadIdx.x;
  __shared__ float lds[64][65];
  #pragma unroll
  for (int i=0;i<16;i++){
    int e = tid + i*256;
    int kl = e >> 6, c = e & 63;
    int np = n0 + c;
    int ns;
    if (split){
      if (np < split) ns = np;
      else if (np >= splitPad && np < splitPad + (N - split)) ns = np - (splitPad - split);
      else ns = -1;
    } else ns = (np < N) ? np : -1;
    int k = k0 + kl;
    float v = (ns >= 0 && k < K) ? W[(long)z*sW + (long)k*N + ns] : 0.f;
    lds[kl][c] = v;
  }
  __syncthreads();
  #pragma unroll
  for (int i=0;i<16;i++){
    int e = tid + i*256;
    int nl = e >> 6, kl = e & 63;
    out[(long)z*sO + (long)(n0+nl)*Kpad + k0 + kl] = __float2bfloat16(lds[kl][nl]);
  }
}

// ---------------- weight transpose+convert with hi/lo split
__global__ __launch_bounds__(256) void convT2_kernel(
    const float* __restrict__ W, int N, int K,
    __hip_bfloat16* __restrict__ outh, __hip_bfloat16* __restrict__ outl,
    int Npad, int Kpad, int split, int splitPad)
{
  int n0 = blockIdx.x*64, k0 = blockIdx.y*64;
  int tid = threadIdx.x;
  __shared__ float lds[64][65];
  #pragma unroll
  for (int i=0;i<16;i++){
    int e = tid + i*256;
    int kl = e >> 6, c = e & 63;
    int np = n0 + c;
    int ns;
    if (split){
      if (np < split) ns = np;
      else if (np >= splitPad && np < splitPad + (N - split)) ns = np - (splitPad - split);
      else ns = -1;
    } else ns = (np < N) ? np : -1;
    int k = k0 + kl;
    float v = (ns >= 0 && k < K) ? W[(long)k*N + ns] : 0.f;
    lds[kl][c] = v;
  }
  __syncthreads();
  #pragma unroll
  for (int i=0;i<16;i++){
    int e = tid + i*256;
    int nl = e >> 6, kl = e & 63;
    float v = lds[kl][nl];
    __hip_bfloat16 h, l; split2(v, h, l);
    long o = (long)(n0+nl)*Kpad + k0 + kl;
    outh[o] = h; outl[o] = l;
  }
}

// ---------------- bias pack for z-batched QKV
__global__ void pack_bias_kernel(const float* bq, const float* bk, const float* bv, float* out){
  int i = blockIdx.x*256 + threadIdx.x;
  if (i < 256) out[i] = bq[i];
  else if (i < 512) out[i] = bk[i-256];
  else if (i < 768) out[i] = bv[i-512];
}

// ---------------- attention prep: Q (scaled) and K fp32 -> hi/lo bf16
__global__ __launch_bounds__(256) void qksplit_kernel(
    const float* __restrict__ QP,
    __hip_bfloat16* __restrict__ qsh, __hip_bfloat16* __restrict__ qsl,
    __hip_bfloat16* __restrict__ ksh, __hip_bfloat16* __restrict__ ksl)
{
  int idx = blockIdx.x*256 + threadIdx.x;   // 1048576
  float qv = QP[idx] * 0.17677669529663687f;
  __hip_bfloat16 h, l;
  split2(qv, h, l); qsh[idx] = h; qsl[idx] = l;
  float kv = QP[1048576 + idx];
  split2(kv, h, l); ksh[idx] = h; ksl[idx] = l;
}

// ---------------- attention prep: V fp32 [s][256] -> V^T hi/lo [bh][32 d][1024 s]
__global__ __launch_bounds__(256) void vtrans_kernel(
    const float* __restrict__ VP,
    __hip_bfloat16* __restrict__ vth, __hip_bfloat16* __restrict__ vtl)
{
  int bh = blockIdx.y, bb = bh >> 3, h = bh & 7;
  int s0 = blockIdx.x*64;
  int tid = threadIdx.x;
  __shared__ float t[64][33];
  #pragma unroll
  for (int p=0;p<8;p++){
    int sl = (tid>>5) + p*8;
    int d = tid & 31;
    t[sl][d] = VP[((bb<<10)+s0+sl)*256 + h*32 + d];
  }
  __syncthreads();
  #pragma unroll
  for (int p=0;p<8;p++){
    int dl = (tid>>6) + p*4;
    int s = tid & 63;
    float v = t[s][dl];
    __hip_bfloat16 hh, ll; split2(v, hh, ll);
    vth[(bh*32+dl)*1024 + s0 + s] = hh;
    vtl[(bh*32+dl)*1024 + s0 + s] = ll;
  }
}

// ---------------- MFMA flash attention v2 (transposed-S softmax + MFMA row-sum)
#define KSP 40
__global__ __launch_bounds__(256) void attn_mfma_kernel(
    const __hip_bfloat16* __restrict__ qsh_, const __hip_bfloat16* __restrict__ qsl_,
    const __hip_bfloat16* __restrict__ ksh_, const __hip_bfloat16* __restrict__ ksl_,
    const __hip_bfloat16* __restrict__ vth_, const __hip_bfloat16* __restrict__ vtl_,
    __hip_bfloat16* __restrict__ aoh, __hip_bfloat16* __restrict__ aol)
{
  const short* qsh = (const short*)qsh_; const short* qsl = (const short*)qsl_;
  const short* ksh = (const short*)ksh_; const short* ksl = (const short*)ksl_;
  const short* vth = (const short*)vth_; const short* vtl = (const short*)vtl_;
  int bh = blockIdx.y, bb = bh >> 3, h = bh & 7;
  int tid = threadIdx.x, lane = tid & 63, wave = tid >> 6;
  int ml = lane & 15, quad = lane >> 4;
  int q0 = blockIdx.x*64 + wave*16;

  __shared__ short KhS[32*KSP], KlS[32*KSP], VhS[32*KSP], VlS[32*KSP];
  __shared__ short PhS[4][16*KSP], PlS[4][16*KSP];
  short* Phw = PhS[wave]; short* Plw = PlS[wave];

  int qrow = (bb<<10) + q0 + ml;
  short8 qfh = *(const short8*)&qsh[qrow*256 + h*32 + quad*8];
  short8 qfl = *(const short8*)&qsl[qrow*256 + h*32 + quad*8];

  short8 ones;
  #pragma unroll
  for (int i=0;i<8;i++) ones[i] = (short)0x3F80;

  f32x4 O0 = {0.f,0.f,0.f,0.f}, O1 = {0.f,0.f,0.f,0.f};
  f32x4 Lacc = {0.f,0.f,0.f,0.f};
  float m_s = -INFINITY;

  int sr = tid >> 3, sc = (tid & 7)*4;
  for (int k0 = 0; k0 < 1024; k0 += 32){
    int krow = (bb<<10) + k0 + sr;
    short4v kvh = *(const short4v*)&ksh[krow*256 + h*32 + sc];
    short4v kvl = *(const short4v*)&ksl[krow*256 + h*32 + sc];
    short4v vvh = *(const short4v*)&vth[(bh*32+sr)*1024 + k0 + sc];
    short4v vvl = *(const short4v*)&vtl[(bh*32+sr)*1024 + k0 + sc];
    __syncthreads();
    *(short4v*)&KhS[sr*KSP + sc] = kvh;
    *(short4v*)&KlS[sr*KSP + sc] = kvl;
    *(short4v*)&VhS[sr*KSP + sc] = vvh;
    *(short4v*)&VlS[sr*KSP + sc] = vvl;
    __syncthreads();
    short8 kb0h = *(const short8*)&KhS[ml*KSP + quad*8];
    short8 kb0l = *(const short8*)&KlS[ml*KSP + quad*8];
    short8 kb1h = *(const short8*)&KhS[(16+ml)*KSP + quad*8];
    short8 kb1l = *(const short8*)&KlS[(16+ml)*KSP + quad*8];
    f32x4 S0 = {0.f,0.f,0.f,0.f}, S1 = {0.f,0.f,0.f,0.f};
    S0 = __builtin_amdgcn_mfma_f32_16x16x32_bf16(kb0l, qfh, S0, 0,0,0);
    S0 = __builtin_amdgcn_mfma_f32_16x16x32_bf16(kb0h, qfl, S0, 0,0,0);
    S0 = __builtin_amdgcn_mfma_f32_16x16x32_bf16(kb0h, qfh, S0, 0,0,0);
    S1 = __builtin_amdgcn_mfma_f32_16x16x32_bf16(kb1l, qfh, S1, 0,0,0);
    S1 = __builtin_amdgcn_mfma_f32_16x16x32_bf16(kb1h, qfl, S1, 0,0,0);
    S1 = __builtin_amdgcn_mfma_f32_16x16x32_bf16(kb1h, qfh, S1, 0,0,0);
    float tm = fmaxf(fmaxf(fmaxf(S0[0],S0[1]), fmaxf(S0[2],S0[3])),
                     fmaxf(fmaxf(S1[0],S1[1]), fmaxf(S1[2],S1[3])));
    tm = fmaxf(tm, __shfl_xor(tm, 16, 64));
    tm = fmaxf(tm, __shfl_xor(tm, 32, 64));
    float nm = fmaxf(m_s, tm);
    float alpha = expf(m_s - nm);
    m_s = nm;
    #pragma unroll
    for (int r=0;r<4;r++){
      float p0 = expf(S0[r] - nm);
      float p1 = expf(S1[r] - nm);
      short sh, sl2;
      split2s(p0, sh, sl2);
      Phw[ml*KSP + quad*4 + r] = sh;       Plw[ml*KSP + quad*4 + r] = sl2;
      split2s(p1, sh, sl2);
      Phw[ml*KSP + 16 + quad*4 + r] = sh;  Plw[ml*KSP + 16 + quad*4 + r] = sl2;
    }
    #pragma unroll
    for (int r=0;r<4;r++){
      float ar = __shfl(alpha, quad*4 + r, 16);
      O0[r] *= ar; O1[r] *= ar; Lacc[r] *= ar;
    }
    short8 pAh = *(const short8*)&Phw[ml*KSP + quad*8];
    short8 pAl = *(const short8*)&Plw[ml*KSP + quad*8];
    short8 vb0h = *(const short8*)&VhS[ml*KSP + quad*8];
    short8 vb0l = *(const short8*)&VlS[ml*KSP + quad*8];
    short8 vb1h = *(const short8*)&VhS[(16+ml)*KSP + quad*8];
    short8 vb1l = *(const short8*)&VlS[(16+ml)*KSP + quad*8];
    O0 = __builtin_amdgcn_mfma_f32_16x16x32_bf16(pAl, vb0h, O0, 0,0,0);
    O0 = __builtin_amdgcn_mfma_f32_16x16x32_bf16(pAh, vb0l, O0, 0,0,0);
    O0 = __builtin_amdgcn_mfma_f32_16x16x32_bf16(pAh, vb0h, O0, 0,0,0);
    O1 = __builtin_amdgcn_mfma_f32_16x16x32_bf16(pAl, vb1h, O1, 0,0,0);
    O1 = __builtin_amdgcn_mfma_f32_16x16x32_bf16(pAh, vb1l, O1, 0,0,0);
    O1 = __builtin_amdgcn_mfma_f32_16x16x32_bf16(pAh, vb1h, O1, 0,0,0);
    Lacc = __builtin_amdgcn_mfma_f32_16x16x32_bf16(pAh, ones, Lacc, 0,0,0);
    Lacc = __builtin_amdgcn_mfma_f32_16x16x32_bf16(pAl, ones, Lacc, 0,0,0);
  }
  #pragma unroll
  for (int r=0;r<4;r++){
    float inv = 1.f / Lacc[r];
    int row = (bb<<10) + q0 + quad*4 + r;
    __hip_bfloat16 hh, ll;
    split2(O0[r]*inv, hh, ll);
    aoh[row*256 + h*32 + ml] = hh;       aol[row*256 + h*32 + ml] = ll;
    split2(O1[r]*inv, hh, ll);
    aoh[row*256 + h*32 + 16 + ml] = hh;  aol[row*256 + h*32 + 16 + ml] = ll;
  }
}

// ---------------- concat queries into x[:, 256:512]
__global__ __launch_bounds__(256) void concat_kernel(
    const float* __restrict__ queries, float* __restrict__ x)
{
  int idx = blockIdx.x*256 + threadIdx.x;
  int d = idx & 255; int r = idx >> 8;
  x[(r<<9) + 256 + d] = queries[idx];
}

// ---------------- rmsnorm fp32 out
__global__ __launch_bounds__(256) void rmsnorm_kernel(
    const float* __restrict__ x, const float* __restrict__ g, float* __restrict__ y)
{
  int r = blockIdx.x; int tid = threadIdx.x;
  float v0 = x[(r<<9) + tid];
  float v1 = x[(r<<9) + 256 + tid];
  float ss = v0*v0 + v1*v1;
  #pragma unroll
  for (int off=32; off>0; off>>=1) ss += __shfl_down(ss, off, 64);
  __shared__ float wsum[4];
  if ((tid & 63) == 0) wsum[tid>>6] = ss;
  __syncthreads();
  float tot = wsum[0]+wsum[1]+wsum[2]+wsum[3];
  float scale = 22.62741699796952f / fmaxf(sqrtf(tot), 1e-12f);
  y[(r<<9) + tid]       = v0*scale*g[tid];
  y[(r<<9) + 256 + tid] = v1*scale*g[256+tid];
}

// ---------------- rmsnorm hi/lo out
__global__ __launch_bounds__(256) void rmsnorm_split_kernel(
    const float* __restrict__ x, const float* __restrict__ g,
    __hip_bfloat16* __restrict__ yh, __hip_bfloat16* __restrict__ yl)
{
  int r = blockIdx.x; int tid = threadIdx.x;
  float v0 = x[(r<<9) + tid];
  float v1 = x[(r<<9) + 256 + tid];
  float ss = v0*v0 + v1*v1;
  #pragma unroll
  for (int off=32; off>0; off>>=1) ss += __shfl_down(ss, off, 64);
  __shared__ float wsum[4];
  if ((tid & 63) == 0) wsum[tid>>6] = ss;
  __syncthreads();
  float tot = wsum[0]+wsum[1]+wsum[2]+wsum[3];
  float scale = 22.62741699796952f / fmaxf(sqrtf(tot), 1e-12f);
  float a = v0*scale*g[tid];
  float b = v1*scale*g[256+tid];
  __hip_bfloat16 h, l;
  split2(a, h, l); yh[(r<<9)+tid] = h;     yl[(r<<9)+tid] = l;
  split2(b, h, l); yh[(r<<9)+256+tid] = h; yl[(r<<9)+256+tid] = l;
}

// ---------------- rmsnorm bf16 out (ffa path)
__global__ __launch_bounds__(256) void rmsnorm_bf_kernel(
    const float* __restrict__ x, const float* __restrict__ g, __hip_bfloat16* __restrict__ y)
{
  int r = blockIdx.x; int tid = threadIdx.x;
  float v0 = x[(r<<9) + tid];
  float v1 = x[(r<<9) + 256 + tid];
  float ss = v0*v0 + v1*v1;
  #pragma unroll
  for (int off=32; off>0; off>>=1) ss += __shfl_down(ss, off, 64);
  __shared__ float wsum[4];
  if ((tid & 63) == 0) wsum[tid>>6] = ss;
  __syncthreads();
  float tot = wsum[0]+wsum[1]+wsum[2]+wsum[3];
  float scale = 22.62741699796952f / fmaxf(sqrtf(tot), 1e-12f);
  y[(r<<9) + tid]       = __float2bfloat16(v0*scale*g[tid]);
  y[(r<<9) + 256 + tid] = __float2bfloat16(v1*scale*g[256+tid]);
}

// ---------------- geglu glu: H fp32 padded [4096][2816] -> T hi/lo [4096][1408]
__global__ __launch_bounds__(256) void glu_split_kernel(
    const float* __restrict__ h, const float* __restrict__ mult,
    __hip_bfloat16* __restrict__ th, __hip_bfloat16* __restrict__ tl)
{
  int idx = blockIdx.x*256 + threadIdx.x;
  int r = idx / 1408; int j = idx - r*1408;
  float v = 0.f;
  if (j < 1365){
    float a  = h[(long)r*2816 + j];
    float gt = h[(long)r*2816 + 1408 + j];
    v = gelu_f(gt) * a * mult[j];
  }
  __hip_bfloat16 hh, ll; split2(v, hh, ll);
  th[idx] = hh; tl[idx] = ll;
}

// ---------------- geglu glu bf16 (ffa path)
__global__ __launch_bounds__(256) void glu_bf_kernel(
    const __hip_bfloat16* __restrict__ h, const float* __restrict__ mult,
    __hip_bfloat16* __restrict__ t)
{
  int idx = blockIdx.x*256 + threadIdx.x;
  int r = idx / 1408; int j = idx - r*1408;
  float v = 0.f;
  if (j < 1365){
    float a  = __bfloat162float(h[(long)r*2816 + j]);
    float gt = __bfloat162float(h[(long)r*2816 + 1408 + j]);
    v = gelu_f(gt) * a * mult[j];
  }
  t[idx] = __float2bfloat16(v);
}

// ---------------- split fp32 -> hi/lo
__global__ __launch_bounds__(256) void split32_kernel(
    const float* __restrict__ x, __hip_bfloat16* __restrict__ h, __hip_bfloat16* __restrict__ l)
{
  int idx = blockIdx.x*256 + threadIdx.x;
  float v = x[idx];
  __hip_bfloat16 hh, ll; split2(v, hh, ll);
  h[idx] = hh; l[idx] = ll;
}

// ---------------- gating v3: per-token block, NO global atomics.
// Stores raw probs + lse^2; aux reduces them later.
__global__ __launch_bounds__(256) void gating_kernel(
    const float* __restrict__ xn, const float* __restrict__ gate_w,
    int* __restrict__ idx1, int* __restrict__ idx2, int* __restrict__ route,
    float* __restrict__ gg1, float* __restrict__ gg2,
    float* __restrict__ rawp, float* __restrict__ lse2)
{
  int t = blockIdx.x; int tid = threadIdx.x;
  __shared__ float xrow[512];
  xrow[tid]     = xn[(t<<9)+tid];
  xrow[256+tid] = xn[(t<<9)+256+tid];
  __syncthreads();
  int e = tid >> 4, l16 = tid & 15;
  float p = 0.f;
  for (int d=l16; d<512; d+=16) p += xrow[d]*gate_w[(e<<9)+d];
  __shared__ float part[16][17];
  part[e][l16] = p;
  __syncthreads();
  __shared__ float raw[16];
  if (tid < 16){
    float s = 0.f;
    #pragma unroll
    for (int i=0;i<16;i++) s += part[tid][i];
    raw[tid] = s;
  }
  __syncthreads();
  if (tid == 0){
    float mx = -1e30f;
    #pragma unroll
    for (int i=0;i<16;i++) mx = fmaxf(mx, raw[i]);
    float r[16]; float sum = 0.f;
    #pragma unroll
    for (int i=0;i<16;i++){ r[i] = expf(raw[i]-mx); sum += r[i]; }
    float lse = mx + logf(sum);
    lse2[t] = lse*lse;
    float inv = 1.f/sum;
    #pragma unroll
    for (int i=0;i<16;i++){ r[i] *= inv; rawp[t*16+i] = r[i]; }
    int i1 = -1; float b1 = -1.f;
    #pragma unroll
    for (int i=0;i<16;i++) if (r[i] > b1){ b1 = r[i]; i1 = i; }
    int i2 = -1; float b2 = -1.f;
    #pragma unroll
    for (int i=0;i<16;i++) if (i != i1 && r[i] > b2){ b2 = r[i]; i2 = i; }
    float s2 = fmaxf(b1 + b2, 1e-9f);
    float g1n = b1/s2, g2n = b2/s2;
    idx1[t] = i1; idx2[t] = i2;
    route[t] = (g2n > 0.2f) ? 1 : 0;
    gg1[t] = g1n; gg2[t] = g2n;
  }
}

// ---------------- capacity assignment: parallel segmented prefix scan
__global__ __launch_bounds__(256) void scan_kernel(
    const int* __restrict__ idx1, const int* __restrict__ idx2, const int* __restrict__ route,
    int* __restrict__ ts1, int* __restrict__ ts2, int* __restrict__ slot_token,
    int* __restrict__ count1)
{
  int bb = blockIdx.x >> 4;
  int e  = blockIdx.x & 15;
  int tid = threadIdx.x;
  int tbase = (bb<<10) + tid*4;
  int4 i1 = *(const int4*)&idx1[tbase];
  int4 i2 = *(const int4*)&idx2[tbase];
  int4 rt = *(const int4*)&route[tbase];
  int m1[4] = { i1.x==e, i1.y==e, i1.z==e, i1.w==e };
  int m2[4] = { i2.x==e, i2.y==e, i2.z==e, i2.w==e };
  int r4[4] = { rt.x, rt.y, rt.z, rt.w };
  int c1 = m1[0]+m1[1]+m1[2]+m1[3];
  int c2 = (m2[0]&&r4[0]) + (m2[1]&&r4[1]) + (m2[2]&&r4[2]) + (m2[3]&&r4[3]);
  __shared__ int s1[256], s2v[256];
  s1[tid] = c1; s2v[tid] = c2;
  __syncthreads();
  for (int off=1; off<256; off<<=1){
    int v1 = (tid>=off) ? s1[tid-off] : 0;
    int v2 = (tid>=off) ? s2v[tid-off] : 0;
    __syncthreads();
    s1[tid] += v1; s2v[tid] += v2;
    __syncthreads();
  }
  int tot1 = s1[255], tot2 = s2v[255];
  int p1 = s1[tid] - c1;
  int p2 = s2v[tid] - c2;
  if (tid == 0) count1[(bb<<4)+e] = tot1;
  int base = ((e<<2)+bb)*CAPN;
  #pragma unroll
  for (int i=0;i<4;i++){
    int t = tbase + i;
    if (m1[i]){
      if (p1 < CAPN){ ts1[t] = base+p1; slot_token[base+p1] = t; }
      else ts1[t] = -1;
      p1++;
    }
    if (m2[i]){
      if (r4[i]){
        int pos = tot1 + p2;
        if (pos < CAPN){ ts2[t] = base+pos; slot_token[base+pos] = t; }
        else ts2[t] = -1;
        p2++;
      } else ts2[t] = -1;
    }
  }
  int filled = min(CAPN, tot1 + tot2);
  if (tid < CAPN && tid >= filled) slot_token[base+tid] = -1;
}

// ---------------- gather + layernorm -> xin bf16
__global__ __launch_bounds__(256) void gather_ln_kernel(
    const float* __restrict__ xn, const int* __restrict__ slot_token,
    const float* __restrict__ ln_g, const float* __restrict__ ln_b,
    __hip_bfloat16* __restrict__ xin)
{
  int s = blockIdx.x; int tid = threadIdx.x;
  int t = slot_token[s];
  int e = s >> 9;
  if (t < 0){
    xin[(s<<9)+tid] = __float2bfloat16(0.f);
    xin[(s<<9)+256+tid] = __float2bfloat16(0.f);
    return;
  }
  float v0 = xn[(t<<9)+tid];
  float v1 = xn[(t<<9)+256+tid];
  float sm = v0+v1, sq = v0*v0+v1*v1;
  #pragma unroll
  for (int off=32; off>0; off>>=1){
    sm += __shfl_down(sm, off, 64);
    sq += __shfl_down(sq, off, 64);
  }
  __shared__ float s1[4], s2buf[4];
  if ((tid & 63) == 0){ s1[tid>>6] = sm; s2buf[tid>>6] = sq; }
  __syncthreads();
  float tsm = s1[0]+s1[1]+s1[2]+s1[3];
  float tsq = s2buf[0]+s2buf[1]+s2buf[2]+s2buf[3];
  float mean = tsm * (1.f/512.f);
  float var = tsq * (1.f/512.f) - mean*mean;
  float rstd = rsqrtf(var + 1e-5f);
  xin[(s<<9)+tid]     = __float2bfloat16((v0-mean)*rstd*ln_g[(e<<9)+tid]     + ln_b[(e<<9)+tid]);
  xin[(s<<9)+256+tid] = __float2bfloat16((v1-mean)*rstd*ln_g[(e<<9)+256+tid] + ln_b[(e<<9)+256+tid]);
}

// ---------------- combine (in-place)
__global__ __launch_bounds__(256) void combine_kernel(
    float* __restrict__ x, const float* __restrict__ h2,
    const int* __restrict__ ts1, const int* __restrict__ ts2,
    const float* __restrict__ gg1, const float* __restrict__ gg2)
{
  int idx = blockIdx.x*256 + threadIdx.x;
  int t = idx >> 9; int d = idx & 511;
  float v = x[idx];
  int s1 = ts1[t]; if (s1 >= 0) v += gg1[t]*h2[(s1<<9)+d];
  int s2 = ts2[t]; if (s2 >= 0) v += gg2[t]*h2[(s2<<9)+d];
  x[idx] = v;
}

// ---------------- aux losses v2: reduces rawp/lse2 (no atomics anywhere)
__global__ __launch_bounds__(256) void aux_kernel(
    const float* __restrict__ rawp, const float* __restrict__ lse2,
    const int* __restrict__ count1, float* __restrict__ out)
{
  __shared__ float accA[256], accZ[256];
  int tid = threadIdx.x;
  int be = tid >> 2, sub = tid & 3;     // 64 (b,e) pairs x 4 sub-strips
  int bb = be >> 4, e = be & 15;
  float s = 0.f;
  int tb = (bb<<10) + sub*256;
  for (int i=0;i<256;i++) s += rawp[(tb+i)*16 + e];
  accA[tid] = s;
  float z = 0.f;
  for (int i=tid; i<4096; i+=256) z += lse2[i];
  accZ[tid] = z;
  __syncthreads();
  if (tid == 0){
    float v = 0.f;
    for (int i=0;i<64;i++){
      float sr = accA[i*4]+accA[i*4+1]+accA[i*4+2]+accA[i*4+3];
      v += (sr*(1.f/1024.f)) * ((float)count1[i]*(1.f/1024.f));
    }
    float zt = 0.f;
    for (int i=0;i<256;i++) zt += accZ[i];
    float bal = v * (1.f/64.f) * 256.f * 0.01f;
    float zl = zt * (1.f/4096.f) * 0.001f;
    out[0] = bal + zl;
    out[1] = bal;
    out[2] = zl;
  }
}

extern "C" void kernel_launch(void* const* d_in, const int* in_sizes, int n_in,
                              void* d_out, int out_size, void* d_ws, size_t ws_size,
                              hipStream_t stream)
{
  const float* K_in   = (const float*)d_in[0];
  const float* V_in   = (const float*)d_in[1];
  const float* Q_in   = (const float*)d_in[2];
  const float* w_topo = (const float*)d_in[3];
  const float* b_topo = (const float*)d_in[4];
  const float* w_val  = (const float*)d_in[5];
  const float* b_val  = (const float*)d_in[6];
  const float* wq     = (const float*)d_in[7];
  const float* bq     = (const float*)d_in[8];
  const float* wk     = (const float*)d_in[9];
  const float* bk     = (const float*)d_in[10];
  const float* wv     = (const float*)d_in[11];
  const float* bv     = (const float*)d_in[12];
  const float* wo     = (const float*)d_in[13];
  const float* bo     = (const float*)d_in[14];
  const float* ffb_g  = (const float*)d_in[15];
  const float* ffb_w1 = (const float*)d_in[16];
  const float* ffb_b1 = (const float*)d_in[17];
  const float* ffb_mult=(const float*)d_in[18];
  const float* ffb_w2 = (const float*)d_in[19];
  const float* ffb_b2 = (const float*)d_in[20];
  const float* prenorm_g=(const float*)d_in[21];
  const float* gate_w = (const float*)d_in[22];
  const float* exp_ln_g=(const float*)d_in[23];
  const float* exp_ln_b=(const float*)d_in[24];
  const float* exp_w1 = (const float*)d_in[25];
  const float* exp_b1 = (const float*)d_in[26];
  const float* exp_w2 = (const float*)d_in[27];
  const float* exp_b2 = (const float*)d_in[28];
  const float* ffa_g  = (const float*)d_in[29];
  const float* ffa_w1 = (const float*)d_in[30];
  const float* ffa_b1 = (const float*)d_in[31];
  const float* ffa_mult=(const float*)d_in[32];
  const float* ffa_w2 = (const float*)d_in[33];
  const float* ffa_b2 = (const float*)d_in[34];
  const float* w_out  = (const float*)d_in[35];
  const float* b_out  = (const float*)d_in[36];
  float* dout = (float*)d_out;

  float* wsf = (float*)d_ws;
  int*   wsi = (int*)d_ws;

  // ---- layout (float offsets) ----
  const size_t A0 = 0;
  const size_t B0 = 11534336;
  const size_t OXA = 17301504;
  const size_t OXB = 19398656;
  const size_t OWP = 21495808;
  const size_t OMI = 21889024;

  __hip_bfloat16* qhi = (__hip_bfloat16*)(wsf + A0);
  __hip_bfloat16* khi = (__hip_bfloat16*)(wsf + A0 + 524288);
  __hip_bfloat16* vhi = (__hip_bfloat16*)(wsf + A0 + 1048576);
  __hip_bfloat16* qlo = (__hip_bfloat16*)(wsf + A0 + 1572864);
  __hip_bfloat16* klo = (__hip_bfloat16*)(wsf + A0 + 2097152);
  __hip_bfloat16* vlo = (__hip_bfloat16*)(wsf + A0 + 2621440);
  float* QP = wsf + A0 + 3145728;
  __hip_bfloat16* aohi = (__hip_bfloat16*)(wsf + A0 + 6291456);
  __hip_bfloat16* aolo = (__hip_bfloat16*)(wsf + A0 + 6815744);
  __hip_bfloat16* qsh = (__hip_bfloat16*)(wsf + A0);
  __hip_bfloat16* qsl = (__hip_bfloat16*)(wsf + A0 + 524288);
  __hip_bfloat16* ksh = (__hip_bfloat16*)(wsf + A0 + 1048576);
  __hip_bfloat16* ksl = (__hip_bfloat16*)(wsf + A0 + 1572864);
  __hip_bfloat16* vth = (__hip_bfloat16*)(wsf + A0 + 2097152);
  __hip_bfloat16* vtl = (__hip_bfloat16*)(wsf + A0 + 2621440);
  float* QF = wsf + B0 + 262144;
  float* Hb = wsf + A0;
  __hip_bfloat16* yh   = (__hip_bfloat16*)(wsf + B0);
  __hip_bfloat16* yl   = (__hip_bfloat16*)(wsf + B0 + 1048576);
  __hip_bfloat16* fw1h = (__hip_bfloat16*)(wsf + B0 + 2097152);
  __hip_bfloat16* fw1l = fw1h + 1441792;
  __hip_bfloat16* th   = (__hip_bfloat16*)(wsf + B0);
  __hip_bfloat16* tl   = (__hip_bfloat16*)(wsf + B0 + 2883584);
  __hip_bfloat16* fw2h = (__hip_bfloat16*)(wsf + A0);
  __hip_bfloat16* fw2l = fw2h + 720896;
  float* Pffb = wsf + A0 + 1048576;
  __hip_bfloat16* wte   = (__hip_bfloat16*)(wsf + A0);
  __hip_bfloat16* xin_bf= (__hip_bfloat16*)(wsf + A0 + 5767168);
  __hip_bfloat16* h1_bf = (__hip_bfloat16*)(wsf + A0 + 7864320);
  float* H2 = wsf + 13631488;
  float* YM = wsf + B0;
  __hip_bfloat16* y_bf = (__hip_bfloat16*)(wsf + A0);
  __hip_bfloat16* wf1  = (__hip_bfloat16*)(wsf + A0 + 1048576);
  __hip_bfloat16* h_bf = (__hip_bfloat16*)(wsf + A0 + 1769472);
  __hip_bfloat16* t_bf = (__hip_bfloat16*)(wsf + A0 + 7536640);
  __hip_bfloat16* wf2  = (__hip_bfloat16*)(wsf + A0 + 10420224);
  float* Pffa = wsf + B0;
  __hip_bfloat16* xah = (__hip_bfloat16*)(wsf + A0);
  __hip_bfloat16* xal = (__hip_bfloat16*)(wsf + A0 + 1048576);
  float* Pout = wsf + A0 + 2097152;
  __hip_bfloat16* wp = (__hip_bfloat16*)(wsf + OWP);
  __hip_bfloat16* wqh = wp;            __hip_bfloat16* wkh = wp + 65536;
  __hip_bfloat16* wvh = wp + 131072;   __hip_bfloat16* wql = wp + 196608;
  __hip_bfloat16* wkl = wp + 262144;   __hip_bfloat16* wvl = wp + 327680;
  __hip_bfloat16* woh = wp + 393216;   __hip_bfloat16* wol = wp + 458752;
  __hip_bfloat16* wouth = wp + 524288; __hip_bfloat16* woutl = wp + 655360;

  int* idx1 = wsi + OMI + 0;
  int* idx2 = wsi + OMI + 4096;
  int* route= wsi + OMI + 8192;
  int* ts1  = wsi + OMI + 12288;
  int* ts2  = wsi + OMI + 16384;
  int* slot_token = wsi + OMI + 20480;
  int* count1     = wsi + OMI + 28672;
  float* gg1      = wsf + OMI + 28864;
  float* gg2      = wsf + OMI + 32960;
  float* bias_qkv = wsf + OMI + 37056;   // 768
  float* rawp     = wsf + OMI + 37824;   // 65536
  float* lse2     = wsf + OMI + 103360;  // 4096

  // ---- phase 0: static weight conversions ----
  convT2_kernel<<<dim3(4,4),  256, 0, stream>>>(wq, 256, 256, wqh, wql, 256, 256, 0, 0);
  convT2_kernel<<<dim3(4,4),  256, 0, stream>>>(wk, 256, 256, wkh, wkl, 256, 256, 0, 0);
  convT2_kernel<<<dim3(4,4),  256, 0, stream>>>(wv, 256, 256, wvh, wvl, 256, 256, 0, 0);
  convT2_kernel<<<dim3(4,4),  256, 0, stream>>>(wo, 256, 256, woh, wol, 256, 256, 0, 0);
  convT2_kernel<<<dim3(4,8),  256, 0, stream>>>(w_out, 256, 512, wouth, woutl, 256, 512, 0, 0);
  convT2_kernel<<<dim3(44,8), 256, 0, stream>>>(ffb_w1, 2730, 512, fw1h, fw1l, 2816, 512, 1365, 1408);
  pack_bias_kernel<<<3, 256, 0, stream>>>(bq, bk, bv, bias_qkv);

  // ---- phase 1: topo / values ----
  topo_kernel<<<8192, 256, 0, stream>>>(K_in, Q_in, w_topo, b_topo, khi, klo, qhi, qlo, QF);
  values_kernel<<<4096, 256, 0, stream>>>(V_in, w_val, b_val, vhi, vlo);

  // ---- phase 2: QKV projections ----
  sgemm_kernel<<<dim3(2,32,3), 256, 0, stream>>>(
      qhi, qlo, 256, 1048576, wqh, wql, 256, 65536,
      bias_qkv, 256, 0, 0, 256, nullptr, 0, QP, 256, 1048576, 256, 0,
      nullptr, 0, 1);

  // ---- phase 3: MFMA flash attention ----
  qksplit_kernel<<<4096, 256, 0, stream>>>(QP, qsh, qsl, ksh, ksl);
  vtrans_kernel<<<dim3(16,32), 256, 0, stream>>>(QP + 2097152, vth, vtl);
  attn_mfma_kernel<<<dim3(16,32), 256, 0, stream>>>(qsh, qsl, ksh, ksl, vth, vtl, aohi, aolo);

  // ---- phase 4: o-proj + concat ----
  sgemm_kernel<<<dim3(2,32,1), 256, 0, stream>>>(
      aohi, aolo, 256, 0, woh, wol, 256, 0,
      bo, 256, 0, 0, 0, nullptr, 0, wsf+OXA, 512, 0, 256, 0,
      nullptr, 0, 1);
  concat_kernel<<<4096, 256, 0, stream>>>(QF, wsf+OXA);

  // ---- phase 5: ffb geglu ----
  rmsnorm_split_kernel<<<4096, 256, 0, stream>>>(wsf+OXA, ffb_g, yh, yl);
  sgemm_kernel<<<dim3(22,32,1), 256, 0, stream>>>(
      yh, yl, 512, 0, fw1h, fw1l, 512, 0,
      ffb_b1, 2730, 1365, 1408, 0, nullptr, 0, Hb, 2816, 0, 512, 0,
      nullptr, 0, 1);
  glu_split_kernel<<<22528, 256, 0, stream>>>(Hb, ffb_mult, th, tl);
  convT2_kernel<<<dim3(8,22), 256, 0, stream>>>(ffb_w2, 512, 1365, fw2h, fw2l, 512, 1408, 0, 0);
  sgemm_kernel<<<dim3(4,32,4), 256, 0, stream>>>(
      th, tl, 1408, 0, fw2h, fw2l, 1408, 0,
      nullptr, 0, 0, 0, 0, nullptr, 0, nullptr, 512, 0, 1408, 0,
      Pffb, 2097152, 4);
  reduce_kernel<<<8192, 256, 0, stream>>>(
      Pffb, 2097152, 4, ffb_b2, wsf+OXA, wsf+OXB, 511, 9, 512, 0, 2097152);

  // ---- phase 6: MoE ----
  rmsnorm_kernel<<<4096, 256, 0, stream>>>(wsf+OXB, prenorm_g, YM);
  gating_kernel<<<4096, 256, 0, stream>>>(YM, gate_w, idx1, idx2, route, gg1, gg2, rawp, lse2);
  scan_kernel<<<64, 256, 0, stream>>>(idx1, idx2, route, ts1, ts2, slot_token, count1);
  gather_ln_kernel<<<8192, 256, 0, stream>>>(YM, slot_token, exp_ln_g, exp_ln_b, xin_bf);
  convT_kernel<<<dim3(22, 8, 16), 256, 0, stream>>>(exp_w1, 1365, 512, (long)512*1365,
                                                    wte, 1408, 512, (long)1408*512, 0, 0);
  bgemm_kernel<<<dim3(11,4,16), 256, 0, stream>>>(
      xin_bf, 512, (long)512*512, wte, 512, (long)1408*512,
      exp_b1, 1365, 0, 0, 1365, nullptr, 0, 0,
      h1_bf, 1408, (long)512*1408, 1, 512, 2,
      nullptr, 0, 1);
  convT_kernel<<<dim3(8, 22, 16), 256, 0, stream>>>(exp_w2, 512, 1365, (long)1365*512,
                                                    wte, 512, 1408, (long)512*1408, 0, 0);
  bgemm_kernel<<<dim3(4,4,16), 256, 0, stream>>>(
      h1_bf, 1408, (long)512*1408, wte, 1408, (long)512*1408,
      exp_b2, 512, 0, 0, 512, nullptr, 0, 0,
      H2, 512, (long)512*512, 0, 1408, 0,
      nullptr, 0, 1);
  combine_kernel<<<8192, 256, 0, stream>>>(wsf+OXB, H2, ts1, ts2, gg1, gg2);
  aux_kernel<<<1, 256, 0, stream>>>(rawp, lse2, count1, dout + 4096*256);

  // ---- phase 7: ffa geglu ----
  rmsnorm_bf_kernel<<<4096, 256, 0, stream>>>(wsf+OXB, ffa_g, y_bf);
  convT_kernel<<<dim3(44, 8, 1), 256, 0, stream>>>(ffa_w1, 2730, 512, 0,
                                                   wf1, 2816, 512, 0, 1365, 1408);
  bgemm_kernel<<<dim3(22,32,1), 256, 0, stream>>>(
      y_bf, 512, 0, wf1, 512, 0,
      ffa_b1, 2730, 1365, 1408, 0, nullptr, 0, 0,
      h_bf, 2816, 0, 1, 512, 0,
      nullptr, 0, 1);
  glu_bf_kernel<<<22528, 256, 0, stream>>>(h_bf, ffa_mult, t_bf);
  convT_kernel<<<dim3(8, 22, 1), 256, 0, stream>>>(ffa_w2, 512, 1365, 0,
                                                   wf2, 512, 1408, 0, 0, 0);
  bgemm_kernel<<<dim3(4,32,2), 256, 0, stream>>>(
      t_bf, 1408, 0, wf2, 1408, 0,
      nullptr, 0, 0, 0, 0, nullptr, 0, 0,
      nullptr, 512, 0, 0, 1408, 0,
      Pffa, 2097152, 2);
  reduce_kernel<<<8192, 256, 0, stream>>>(
      Pffa, 2097152, 2, ffa_b2, wsf+OXB, wsf+OXA, 511, 9, 512, 0, 2097152);

  // ---- phase 8: out = gelu(XA @ w_out + b_out), split-K=4 ----
  split32_kernel<<<8192, 256, 0, stream>>>(wsf+OXA, xah, xal);
  sgemm_kernel<<<dim3(2,32,4), 256, 0, stream>>>(
      xah, xal, 512, 0, wouth, woutl, 512, 0,
      nullptr, 0, 0, 0, 0, nullptr, 0, nullptr, 256, 0, 512, 0,
      Pout, 1048576, 4);
  reduce_kernel<<<4096, 256, 0, stream>>>(
      Pout, 1048576, 4, b_out, nullptr, dout, 255, 8, 256, 1, 1048576);
}